// Round 1
// baseline (1218.399 us; speedup 1.0000x reference)
//
#include <hip/hip_runtime.h>
#include <hip/hip_bf16.h>
#include <cstdint>
#include <cstddef>

#define LRELU_ALPHA 0.2f

// ---------------- CSR build ----------------

__global__ void hist_k(const int* __restrict__ rows, int* __restrict__ counts, int E_) {
    int e = blockIdx.x * 256 + threadIdx.x;
    if (e < E_) atomicAdd(&counts[rows[e]], 1);
}

__global__ void scan_block_k(const int* __restrict__ counts, int* __restrict__ tmp,
                             int* __restrict__ bsum, int n) {
    __shared__ int s[256];
    int i = blockIdx.x * 256 + threadIdx.x;
    int v = (i < n) ? counts[i] : 0;
    s[threadIdx.x] = v;
    __syncthreads();
    for (int d = 1; d < 256; d <<= 1) {
        int t_ = (threadIdx.x >= d) ? s[threadIdx.x - d] : 0;
        __syncthreads();
        s[threadIdx.x] += t_;
        __syncthreads();
    }
    if (i < n) tmp[i] = s[threadIdx.x];
    if (threadIdx.x == 255) bsum[blockIdx.x] = s[255];
}

__global__ void scan_sums_k(int* bsum, int nb) {
    __shared__ int s[512];
    int v = ((int)threadIdx.x < nb) ? bsum[threadIdx.x] : 0;
    s[threadIdx.x] = v;
    __syncthreads();
    for (int d = 1; d < 512; d <<= 1) {
        int t_ = ((int)threadIdx.x >= d) ? s[threadIdx.x - d] : 0;
        __syncthreads();
        s[threadIdx.x] += t_;
        __syncthreads();
    }
    if ((int)threadIdx.x < nb) bsum[threadIdx.x] = s[threadIdx.x] - v;  // exclusive
}

__global__ void finalize_k(const int* __restrict__ tmp, const int* __restrict__ counts,
                           const int* __restrict__ bsum, int* __restrict__ off,
                           int* __restrict__ cursor, int n) {
    int i = blockIdx.x * 256 + threadIdx.x;
    if (i < n) {
        int incl = tmp[i] + bsum[blockIdx.x];
        off[i + 1] = incl;
        cursor[i] = incl - counts[i];
    }
    if (i == 0) off[0] = 0;
}

__global__ void scatter_k(const int* __restrict__ ei, int* __restrict__ cursor,
                          int* __restrict__ scol, int E_) {
    int e = blockIdx.x * 256 + threadIdx.x;
    if (e < E_) {
        int r = ei[e];
        int pos = atomicAdd(&cursor[r], 1);
        scol[pos] = ei[E_ + e];
    }
}

// W_hid[l] is [4][128][32]; repack to Wcat[k*128 + hd*32 + j]
__global__ void repack_k(const float* __restrict__ Wl, float* __restrict__ Wc) {
    int i = blockIdx.x * 256 + threadIdx.x;
    if (i < 128 * 128) {
        int k = i >> 7, c = i & 127;
        int hd = c >> 5, j = c & 31;
        Wc[i] = Wl[(hd * 128 + k) * 32 + j];
    }
}

// ---------------- GEMM: Y[n, 0:KJ] = act(X[n, 0:128] @ W[128, KJ] + bias) ----------------
// 128-row x KJ-col tile per block, BK=32 k-chunks, 8 x (KJ/16) micro-tile, 256 threads.

template <int KJ, bool ELU_ACT, bool BIAS>
__global__ __launch_bounds__(256) void gemm_k128(const float* __restrict__ X,
                                                 const float* __restrict__ W,
                                                 const float* __restrict__ bias,
                                                 float* __restrict__ Y, int nRows) {
    constexpr int BK = 32;
    constexpr int XS = 132;       // sXT row stride (pad +4: conflict-free reads, aligned)
    constexpr int WS = KJ + 4;
    constexpr int MC = KJ / 16;   // micro cols per thread (8 or 4)
    __shared__ float sXT[BK * XS];   // sXT[k*XS + r]
    __shared__ float sW[BK * WS];    // sW[k*WS + c]
    int t = threadIdx.x;
    int tc = t & 15, tr = t >> 4;
    int rowBase = blockIdx.x * 128;
    int r0 = tr * 8;
    int c0 = tc * MC;
    float acc[8][MC] = {};

    for (int kc = 0; kc < 128; kc += BK) {
        // stage X chunk transposed (coalesced float4 global reads)
        #pragma unroll
        for (int ii = 0; ii < 4; ii++) {
            int i = t + ii * 256;     // 1024 float4s: 128 rows x 8
            int r = i >> 3;
            int k4 = i & 7;
            int gr = rowBase + r;
            float4 v = make_float4(0.f, 0.f, 0.f, 0.f);
            if (gr < nRows) v = *(const float4*)&X[gr * 128 + kc + k4 * 4];
            sXT[(k4 * 4 + 0) * XS + r] = v.x;
            sXT[(k4 * 4 + 1) * XS + r] = v.y;
            sXT[(k4 * 4 + 2) * XS + r] = v.z;
            sXT[(k4 * 4 + 3) * XS + r] = v.w;
        }
        // stage W chunk
        for (int i = t; i < BK * KJ / 4; i += 256) {
            int k = i / (KJ / 4);
            int c4 = i % (KJ / 4);
            float4 v = *(const float4*)&W[(kc + k) * KJ + c4 * 4];
            *(float4*)&sW[k * WS + c4 * 4] = v;
        }
        __syncthreads();
        #pragma unroll
        for (int k = 0; k < BK; k++) {
            float xv[8], wv[MC];
            *(float4*)&xv[0] = *(const float4*)&sXT[k * XS + r0];
            *(float4*)&xv[4] = *(const float4*)&sXT[k * XS + r0 + 4];
            #pragma unroll
            for (int c = 0; c < MC; c += 4)
                *(float4*)&wv[c] = *(const float4*)&sW[k * WS + c0 + c];
            #pragma unroll
            for (int rr = 0; rr < 8; rr++)
                #pragma unroll
                for (int cc = 0; cc < MC; cc++)
                    acc[rr][cc] = fmaf(xv[rr], wv[cc], acc[rr][cc]);
        }
        __syncthreads();
    }
    #pragma unroll
    for (int rr = 0; rr < 8; rr++) {
        int gr = rowBase + r0 + rr;
        if (gr < nRows) {
            #pragma unroll
            for (int cc = 0; cc < MC; cc += 4) {
                float4 v;
                float* vp = (float*)&v;
                #pragma unroll
                for (int q = 0; q < 4; q++) {
                    float val = acc[rr][cc + q];
                    if (BIAS) val += bias[c0 + cc + q];
                    if (ELU_ACT) val = val > 0.f ? val : (__expf(val) - 1.f);
                    vp[q] = val;
                }
                *(float4*)&Y[gr * KJ + c0 + cc] = v;
            }
        }
    }
}

// ---------------- attention scores: s_src/s_dst[n][hd] = h[n,:] . a[hd][side][:] ----------------

template <int H>
__global__ __launch_bounds__(256) void attn_scores(const float* __restrict__ h,
                                                   const float* __restrict__ a,
                                                   float* __restrict__ s_src,
                                                   float* __restrict__ s_dst, int n) {
    __shared__ float sa[H * 2 * 128];
    for (int i = threadIdx.x; i < H * 2 * 128; i += 256) sa[i] = a[i];
    __syncthreads();
    int lane = threadIdx.x & 63, wv = threadIdx.x >> 6;
    int node = blockIdx.x * 4 + wv;
    if (node >= n) return;
    float h0 = h[node * 128 + lane];
    float h1 = h[node * 128 + 64 + lane];
    #pragma unroll
    for (int hd = 0; hd < H; hd++) {
        #pragma unroll
        for (int side = 0; side < 2; side++) {
            const float* av = &sa[(hd * 2 + side) * 128];
            float p = h0 * av[lane] + h1 * av[64 + lane];
            #pragma unroll
            for (int s = 32; s > 0; s >>= 1) p += __shfl_xor(p, s);
            if (lane == 0) {
                float* dst = side ? s_dst : s_src;
                dst[node * H + hd] = p;
            }
        }
    }
}

// ---------------- edge pass: segment softmax (by row) + aggregate hW[col] ----------------
// one wave per destination row; lane = feature (FPL features per lane)

template <int DHT, int H, bool ELU_ACT>
__global__ __launch_bounds__(256) void edge_agg(const float* __restrict__ hW,
                                                const float* __restrict__ s_src,
                                                const float* __restrict__ s_dst,
                                                const int* __restrict__ off,
                                                const int* __restrict__ scol,
                                                float* __restrict__ out, int nRows) {
    constexpr int FPL = DHT / 64;  // features per lane: 2 (hidden) or 1 (final)
    int lane = threadIdx.x & 63;
    int wv = threadIdx.x >> 6;
    int r = blockIdx.x * 4 + wv;
    if (r >= nRows) return;
    int begin = off[r], end = off[r + 1];

    float ss[H];
    #pragma unroll
    for (int h = 0; h < H; h++) ss[h] = s_src[r * H + h];

    // pass 1: segment max (edge-parallel across lanes)
    float m[H];
    #pragma unroll
    for (int h = 0; h < H; h++) m[h] = -3.4e38f;
    for (int i = begin + lane; i < end; i += 64) {
        int c = scol[i];
        if (H == 4) {
            float4 q = *(const float4*)&s_dst[c * 4];
            float lg0 = ss[0] + q.x; lg0 = lg0 > 0.f ? lg0 : LRELU_ALPHA * lg0;
            float lg1 = ss[1] + q.y; lg1 = lg1 > 0.f ? lg1 : LRELU_ALPHA * lg1;
            float lg2 = ss[2] + q.z; lg2 = lg2 > 0.f ? lg2 : LRELU_ALPHA * lg2;
            float lg3 = ss[3] + q.w; lg3 = lg3 > 0.f ? lg3 : LRELU_ALPHA * lg3;
            m[0] = fmaxf(m[0], lg0);
            if (H > 1) { m[1] = fmaxf(m[1], lg1); m[2] = fmaxf(m[2], lg2); m[3] = fmaxf(m[3], lg3); }
        } else {
            float lg = ss[0] + s_dst[c];
            lg = lg > 0.f ? lg : LRELU_ALPHA * lg;
            m[0] = fmaxf(m[0], lg);
        }
    }
    #pragma unroll
    for (int s = 32; s > 0; s >>= 1)
        #pragma unroll
        for (int h = 0; h < H; h++) m[h] = fmaxf(m[h], __shfl_xor(m[h], s));

    // per-lane head selection (feature f = p*64+lane, head = f / (DHT/H))
    float ssl[FPL], ml[FPL];
    bool lo = (lane & 32) == 0;
    if (H == 4) {
        ssl[0] = lo ? ss[0] : ss[1];
        ml[0] = lo ? m[0] : m[1];
        if (FPL == 2) { ssl[1] = lo ? ss[2] : ss[3]; ml[1] = lo ? m[2] : m[3]; }
    } else {
        #pragma unroll
        for (int p = 0; p < FPL; p++) { ssl[p] = ss[0]; ml[p] = m[0]; }
    }

    // pass 2: edge-sequential, feature-parallel
    float accv[FPL] = {};
    float denom[FPL] = {};
    for (int i = begin; i < end; i++) {
        int c = scol[i];
        float sdl[FPL];
        if (H == 4) {
            float4 q = *(const float4*)&s_dst[c * 4];
            sdl[0] = lo ? q.x : q.y;
            if (FPL == 2) sdl[1] = lo ? q.z : q.w;
        } else {
            #pragma unroll
            for (int p = 0; p < FPL; p++) sdl[p] = s_dst[c];
        }
        #pragma unroll
        for (int p = 0; p < FPL; p++) {
            float lg = ssl[p] + sdl[p];
            lg = lg > 0.f ? lg : LRELU_ALPHA * lg;
            float wgt = __expf(lg - ml[p]);
            denom[p] += wgt;
            accv[p] = fmaf(wgt, hW[c * DHT + p * 64 + lane], accv[p]);
        }
    }
    #pragma unroll
    for (int p = 0; p < FPL; p++) {
        float v = denom[p] > 0.f ? accv[p] / denom[p] : 0.f;
        if (ELU_ACT) v = v > 0.f ? v : (__expf(v) - 1.f);
        out[r * DHT + p * 64 + lane] = v;
    }
}

// ---------------- launcher ----------------

extern "C" void kernel_launch(void* const* d_in, const int* in_sizes, int n_in,
                              void* d_out, int out_size, void* d_ws, size_t ws_size,
                              hipStream_t stream) {
    const float* x    = (const float*)d_in[0];
    const int*   ei   = (const int*)d_in[1];
    const float* Win  = (const float*)d_in[2];
    const float* bin  = (const float*)d_in[3];
    const float* ahid = (const float*)d_in[4];
    const float* Whid = (const float*)d_in[5];
    const float* aout = (const float*)d_in[6];
    const float* Wout = (const float*)d_in[7];
    float* out = (float*)d_out;

    const int N_ = in_sizes[0] / 128;
    const int E_ = in_sizes[1] / 2;

    char* p = (char*)d_ws;
    auto alloc = [&](size_t bytes) {
        char* q = p;
        p += (bytes + 511) & ~(size_t)511;
        return q;
    };
    int* counts = (int*)alloc((size_t)N_ * 4);
    int* tmp    = (int*)alloc((size_t)N_ * 4);
    int* cursor = (int*)alloc((size_t)N_ * 4);
    int* off    = (int*)alloc((size_t)(N_ + 1) * 4);
    int* bsum   = (int*)alloc(4096);
    int* scol   = (int*)alloc((size_t)E_ * 4);
    float* ssrc = (float*)alloc((size_t)N_ * 4 * 4);
    float* sdst = (float*)alloc((size_t)N_ * 4 * 4);
    float* bufA = (float*)alloc((size_t)N_ * 128 * 4);
    float* bufB = (float*)alloc((size_t)N_ * 128 * 4);
    float* Wcat = (float*)alloc(128 * 128 * 4);

    int NB = (N_ + 255) / 256;
    int EB = (E_ + 255) / 256;
    int RT = (N_ + 127) / 128;
    int NW = (N_ + 3) / 4;

    // CSR by destination (= edge_index[0], the softmax segment key)
    hipMemsetAsync(counts, 0, (size_t)N_ * 4, stream);
    hist_k<<<EB, 256, 0, stream>>>(ei, counts, E_);
    scan_block_k<<<NB, 256, 0, stream>>>(counts, tmp, bsum, N_);
    scan_sums_k<<<1, 512, 0, stream>>>(bsum, NB);
    finalize_k<<<NB, 256, 0, stream>>>(tmp, counts, bsum, off, cursor, N_);
    scatter_k<<<EB, 256, 0, stream>>>(ei, cursor, scol, E_);

    // input linear + ELU
    gemm_k128<128, true, true><<<RT, 256, 0, stream>>>(x, Win, bin, bufA, N_);

    // hidden GAT layers
    for (int l = 0; l < 2; l++) {
        attn_scores<4><<<NW, 256, 0, stream>>>(bufA, ahid + (size_t)l * 4 * 2 * 128, ssrc, sdst, N_);
        repack_k<<<64, 256, 0, stream>>>(Whid + (size_t)l * 4 * 128 * 32, Wcat);
        gemm_k128<128, false, false><<<RT, 256, 0, stream>>>(bufA, Wcat, nullptr, bufB, N_);
        edge_agg<128, 4, true><<<NW, 256, 0, stream>>>(bufB, ssrc, sdst, off, scol, bufA, N_);
    }

    // output GAT layer (single head, 64 classes, no activation)
    attn_scores<1><<<NW, 256, 0, stream>>>(bufA, aout, ssrc, sdst, N_);
    gemm_k128<64, false, false><<<RT, 256, 0, stream>>>(bufA, Wout, nullptr, bufB, N_);
    edge_agg<64, 1, false><<<NW, 256, 0, stream>>>(bufB, ssrc, sdst, off, scol, out, N_);
}

// Round 2
// 987.248 us; speedup vs baseline: 1.2341x; 1.2341x over previous
//
#include <hip/hip_runtime.h>
#include <hip/hip_bf16.h>
#include <cstdint>
#include <cstddef>

#define LRELU_ALPHA 0.2f

// ---------------- CSR build ----------------

__global__ void hist_k(const int* __restrict__ rows, int* __restrict__ counts, int E_) {
    int e = blockIdx.x * 256 + threadIdx.x;
    if (e < E_) atomicAdd(&counts[rows[e]], 1);
}

__global__ void scan_block_k(const int* __restrict__ counts, int* __restrict__ tmp,
                             int* __restrict__ bsum, int n) {
    __shared__ int s[256];
    int i = blockIdx.x * 256 + threadIdx.x;
    int v = (i < n) ? counts[i] : 0;
    s[threadIdx.x] = v;
    __syncthreads();
    for (int d = 1; d < 256; d <<= 1) {
        int t_ = (threadIdx.x >= d) ? s[threadIdx.x - d] : 0;
        __syncthreads();
        s[threadIdx.x] += t_;
        __syncthreads();
    }
    if (i < n) tmp[i] = s[threadIdx.x];
    if (threadIdx.x == 255) bsum[blockIdx.x] = s[255];
}

__global__ void scan_sums_k(int* bsum, int nb) {
    __shared__ int s[512];
    int v = ((int)threadIdx.x < nb) ? bsum[threadIdx.x] : 0;
    s[threadIdx.x] = v;
    __syncthreads();
    for (int d = 1; d < 512; d <<= 1) {
        int t_ = ((int)threadIdx.x >= d) ? s[threadIdx.x - d] : 0;
        __syncthreads();
        s[threadIdx.x] += t_;
        __syncthreads();
    }
    if ((int)threadIdx.x < nb) bsum[threadIdx.x] = s[threadIdx.x] - v;  // exclusive
}

__global__ void finalize_k(const int* __restrict__ tmp, const int* __restrict__ counts,
                           const int* __restrict__ bsum, int* __restrict__ off,
                           int* __restrict__ cursor, int n) {
    int i = blockIdx.x * 256 + threadIdx.x;
    if (i < n) {
        int incl = tmp[i] + bsum[blockIdx.x];
        off[i + 1] = incl;
        cursor[i] = incl - counts[i];
    }
    if (i == 0) off[0] = 0;
}

__global__ void scatter_k(const int* __restrict__ ei, int* __restrict__ cursor,
                          int* __restrict__ scol, int* __restrict__ srow, int E_) {
    int e = blockIdx.x * 256 + threadIdx.x;
    if (e < E_) {
        int r = ei[e];
        int pos = atomicAdd(&cursor[r], 1);
        scol[pos] = ei[E_ + e];
        srow[pos] = r;
    }
}

// W_hid[l] is [4][128][32]; repack to Wcat[k*128 + hd*32 + j]
__global__ void repack_k(const float* __restrict__ Wl, float* __restrict__ Wc) {
    int i = blockIdx.x * 256 + threadIdx.x;
    if (i < 128 * 128) {
        int k = i >> 7, c = i & 127;
        int hd = c >> 5, j = c & 31;
        Wc[i] = Wl[(hd * 128 + k) * 32 + j];
    }
}

// ---------------- GEMM: Y[n, 0:KJ] = act(X[n, 0:128] @ W[128, KJ] + bias) ----------------

template <int KJ, bool ELU_ACT, bool BIAS>
__global__ __launch_bounds__(256) void gemm_k128(const float* __restrict__ X,
                                                 const float* __restrict__ W,
                                                 const float* __restrict__ bias,
                                                 float* __restrict__ Y, int nRows) {
    constexpr int BK = 32;
    constexpr int XS = 132;
    constexpr int WS = KJ + 4;
    constexpr int MC = KJ / 16;
    __shared__ float sXT[BK * XS];
    __shared__ float sW[BK * WS];
    int t = threadIdx.x;
    int tc = t & 15, tr = t >> 4;
    int rowBase = blockIdx.x * 128;
    int r0 = tr * 8;
    int c0 = tc * MC;
    float acc[8][MC] = {};

    for (int kc = 0; kc < 128; kc += BK) {
        #pragma unroll
        for (int ii = 0; ii < 4; ii++) {
            int i = t + ii * 256;
            int r = i >> 3;
            int k4 = i & 7;
            int gr = rowBase + r;
            float4 v = make_float4(0.f, 0.f, 0.f, 0.f);
            if (gr < nRows) v = *(const float4*)&X[gr * 128 + kc + k4 * 4];
            sXT[(k4 * 4 + 0) * XS + r] = v.x;
            sXT[(k4 * 4 + 1) * XS + r] = v.y;
            sXT[(k4 * 4 + 2) * XS + r] = v.z;
            sXT[(k4 * 4 + 3) * XS + r] = v.w;
        }
        for (int i = t; i < BK * KJ / 4; i += 256) {
            int k = i / (KJ / 4);
            int c4 = i % (KJ / 4);
            float4 v = *(const float4*)&W[(kc + k) * KJ + c4 * 4];
            *(float4*)&sW[k * WS + c4 * 4] = v;
        }
        __syncthreads();
        #pragma unroll
        for (int k = 0; k < BK; k++) {
            float xv[8], wv[MC];
            *(float4*)&xv[0] = *(const float4*)&sXT[k * XS + r0];
            *(float4*)&xv[4] = *(const float4*)&sXT[k * XS + r0 + 4];
            #pragma unroll
            for (int c = 0; c < MC; c += 4)
                *(float4*)&wv[c] = *(const float4*)&sW[k * WS + c0 + c];
            #pragma unroll
            for (int rr = 0; rr < 8; rr++)
                #pragma unroll
                for (int cc = 0; cc < MC; cc++)
                    acc[rr][cc] = fmaf(xv[rr], wv[cc], acc[rr][cc]);
        }
        __syncthreads();
    }
    #pragma unroll
    for (int rr = 0; rr < 8; rr++) {
        int gr = rowBase + r0 + rr;
        if (gr < nRows) {
            #pragma unroll
            for (int cc = 0; cc < MC; cc += 4) {
                float4 v;
                float* vp = (float*)&v;
                #pragma unroll
                for (int q = 0; q < 4; q++) {
                    float val = acc[rr][cc + q];
                    if (BIAS) val += bias[c0 + cc + q];
                    if (ELU_ACT) val = val > 0.f ? val : (__expf(val) - 1.f);
                    vp[q] = val;
                }
                *(float4*)&Y[gr * KJ + c0 + cc] = v;
            }
        }
    }
}

// ---------------- attention scores ----------------

template <int H>
__global__ __launch_bounds__(256) void attn_scores(const float* __restrict__ h,
                                                   const float* __restrict__ a,
                                                   float* __restrict__ s_src,
                                                   float* __restrict__ s_dst, int n) {
    __shared__ float sa[H * 2 * 128];
    for (int i = threadIdx.x; i < H * 2 * 128; i += 256) sa[i] = a[i];
    __syncthreads();
    int lane = threadIdx.x & 63, wv = threadIdx.x >> 6;
    int node = blockIdx.x * 4 + wv;
    if (node >= n) return;
    float h0 = h[node * 128 + lane];
    float h1 = h[node * 128 + 64 + lane];
    #pragma unroll
    for (int hd = 0; hd < H; hd++) {
        #pragma unroll
        for (int side = 0; side < 2; side++) {
            const float* av = &sa[(hd * 2 + side) * 128];
            float p = h0 * av[lane] + h1 * av[64 + lane];
            #pragma unroll
            for (int s = 32; s > 0; s >>= 1) p += __shfl_xor(p, s);
            if (lane == 0) {
                float* dst = side ? s_dst : s_src;
                dst[node * H + hd] = p;
            }
        }
    }
}

// ---------------- edge weights: w[i] = exp(leaky_relu(ssrc[srow[i]] + sdst[scol[i]])) ----------------
// No max-subtraction: |logit| <= ~8 by construction, exp is safe in fp32.

template <int H>
__global__ __launch_bounds__(256) void wexp_k(const float* __restrict__ ssrc,
                                              const float* __restrict__ sdst,
                                              const int* __restrict__ srow,
                                              const int* __restrict__ scol,
                                              float* __restrict__ wbuf, int E_) {
    int i = blockIdx.x * 256 + threadIdx.x;
    if (i >= E_) return;
    int r = srow[i], c = scol[i];
    if (H == 4) {
        float4 a = *(const float4*)&ssrc[r * 4];
        float4 b = *(const float4*)&sdst[c * 4];
        float4 w;
        float lg;
        lg = a.x + b.x; lg = lg > 0.f ? lg : LRELU_ALPHA * lg; w.x = __expf(lg);
        lg = a.y + b.y; lg = lg > 0.f ? lg : LRELU_ALPHA * lg; w.y = __expf(lg);
        lg = a.z + b.z; lg = lg > 0.f ? lg : LRELU_ALPHA * lg; w.z = __expf(lg);
        lg = a.w + b.w; lg = lg > 0.f ? lg : LRELU_ALPHA * lg; w.w = __expf(lg);
        *(float4*)&wbuf[i * 4] = w;
    } else {
        float lg = ssrc[r] + sdst[c];
        lg = lg > 0.f ? lg : LRELU_ALPHA * lg;
        wbuf[i] = __expf(lg);
    }
}

// ---------------- edge aggregation: out[r] = (sum_i w_i * hW[col_i]) / (sum_i w_i) ----------------
// one wave per destination row; lane = feature; unroll x4 with prefetch for MLP.

template <int DHT, int H, bool ELU_ACT>
__global__ __launch_bounds__(256) void edge_agg2(const float* __restrict__ hW,
                                                 const float* __restrict__ wbuf,
                                                 const int* __restrict__ off,
                                                 const int* __restrict__ scol,
                                                 float* __restrict__ out, int nRows) {
    constexpr int FPL = DHT / 64;  // features per lane
    int lane = threadIdx.x & 63;
    int wv = threadIdx.x >> 6;
    int r = blockIdx.x * 4 + wv;
    if (r >= nRows) return;
    int begin = off[r], end = off[r + 1];

    float accv[FPL] = {};
    float den[FPL] = {};
    bool lo = (lane & 32) == 0;

    int i = begin;
    for (; i + 4 <= end; i += 4) {
        int c0 = scol[i], c1 = scol[i + 1], c2 = scol[i + 2], c3 = scol[i + 3];
        float wl[4][FPL];
        if (H == 4) {
            float4 w0 = *(const float4*)&wbuf[(size_t)i * 4];
            float4 w1 = *(const float4*)&wbuf[(size_t)(i + 1) * 4];
            float4 w2 = *(const float4*)&wbuf[(size_t)(i + 2) * 4];
            float4 w3 = *(const float4*)&wbuf[(size_t)(i + 3) * 4];
            wl[0][0] = lo ? w0.x : w0.y; wl[1][0] = lo ? w1.x : w1.y;
            wl[2][0] = lo ? w2.x : w2.y; wl[3][0] = lo ? w3.x : w3.y;
            if (FPL == 2) {
                wl[0][1] = lo ? w0.z : w0.w; wl[1][1] = lo ? w1.z : w1.w;
                wl[2][1] = lo ? w2.z : w2.w; wl[3][1] = lo ? w3.z : w3.w;
            }
        } else {
            float w0 = wbuf[i], w1 = wbuf[i + 1], w2 = wbuf[i + 2], w3 = wbuf[i + 3];
            #pragma unroll
            for (int p = 0; p < FPL; p++) { wl[0][p] = w0; wl[1][p] = w1; wl[2][p] = w2; wl[3][p] = w3; }
        }
        float hv[4][FPL];
        #pragma unroll
        for (int p = 0; p < FPL; p++) {
            hv[0][p] = hW[(size_t)c0 * DHT + p * 64 + lane];
            hv[1][p] = hW[(size_t)c1 * DHT + p * 64 + lane];
            hv[2][p] = hW[(size_t)c2 * DHT + p * 64 + lane];
            hv[3][p] = hW[(size_t)c3 * DHT + p * 64 + lane];
        }
        #pragma unroll
        for (int j = 0; j < 4; j++)
            #pragma unroll
            for (int p = 0; p < FPL; p++) {
                den[p] += wl[j][p];
                accv[p] = fmaf(wl[j][p], hv[j][p], accv[p]);
            }
    }
    for (; i < end; i++) {
        int c = scol[i];
        float wl[FPL];
        if (H == 4) {
            float4 w = *(const float4*)&wbuf[(size_t)i * 4];
            wl[0] = lo ? w.x : w.y;
            if (FPL == 2) wl[1] = lo ? w.z : w.w;
        } else {
            #pragma unroll
            for (int p = 0; p < FPL; p++) wl[p] = wbuf[i];
        }
        #pragma unroll
        for (int p = 0; p < FPL; p++) {
            den[p] += wl[p];
            accv[p] = fmaf(wl[p], hW[(size_t)c * DHT + p * 64 + lane], accv[p]);
        }
    }

    #pragma unroll
    for (int p = 0; p < FPL; p++) {
        float v = den[p] > 0.f ? accv[p] / den[p] : 0.f;
        if (ELU_ACT) v = v > 0.f ? v : (__expf(v) - 1.f);
        out[(size_t)r * DHT + p * 64 + lane] = v;
    }
}

// ---------------- launcher ----------------

extern "C" void kernel_launch(void* const* d_in, const int* in_sizes, int n_in,
                              void* d_out, int out_size, void* d_ws, size_t ws_size,
                              hipStream_t stream) {
    const float* x    = (const float*)d_in[0];
    const int*   ei   = (const int*)d_in[1];
    const float* Win  = (const float*)d_in[2];
    const float* bin  = (const float*)d_in[3];
    const float* ahid = (const float*)d_in[4];
    const float* Whid = (const float*)d_in[5];
    const float* aout = (const float*)d_in[6];
    const float* Wout = (const float*)d_in[7];
    float* out = (float*)d_out;

    const int N_ = in_sizes[0] / 128;
    const int E_ = in_sizes[1] / 2;

    char* p = (char*)d_ws;
    auto alloc = [&](size_t bytes) {
        char* q = p;
        p += (bytes + 511) & ~(size_t)511;
        return q;
    };
    int* counts = (int*)alloc((size_t)N_ * 4);
    int* tmp    = (int*)alloc((size_t)N_ * 4);
    int* cursor = (int*)alloc((size_t)N_ * 4);
    int* off    = (int*)alloc((size_t)(N_ + 1) * 4);
    int* bsum   = (int*)alloc(4096);
    int* scol   = (int*)alloc((size_t)E_ * 4);
    int* srow   = (int*)alloc((size_t)E_ * 4);
    float* wbuf = (float*)alloc((size_t)E_ * 4 * 4);
    float* ssrc = (float*)alloc((size_t)N_ * 4 * 4);
    float* sdst = (float*)alloc((size_t)N_ * 4 * 4);
    float* bufA = (float*)alloc((size_t)N_ * 128 * 4);
    float* bufB = (float*)alloc((size_t)N_ * 128 * 4);
    float* Wcat = (float*)alloc(128 * 128 * 4);

    int NB = (N_ + 255) / 256;
    int EB = (E_ + 255) / 256;
    int RT = (N_ + 127) / 128;
    int NW = (N_ + 3) / 4;

    // CSR by destination (= edge_index[0], the softmax segment key)
    hipMemsetAsync(counts, 0, (size_t)N_ * 4, stream);
    hist_k<<<EB, 256, 0, stream>>>(ei, counts, E_);
    scan_block_k<<<NB, 256, 0, stream>>>(counts, tmp, bsum, N_);
    scan_sums_k<<<1, 512, 0, stream>>>(bsum, NB);
    finalize_k<<<NB, 256, 0, stream>>>(tmp, counts, bsum, off, cursor, N_);
    scatter_k<<<EB, 256, 0, stream>>>(ei, cursor, scol, srow, E_);

    // input linear + ELU
    gemm_k128<128, true, true><<<RT, 256, 0, stream>>>(x, Win, bin, bufA, N_);

    // hidden GAT layers
    for (int l = 0; l < 2; l++) {
        attn_scores<4><<<NW, 256, 0, stream>>>(bufA, ahid + (size_t)l * 4 * 2 * 128, ssrc, sdst, N_);
        wexp_k<4><<<EB, 256, 0, stream>>>(ssrc, sdst, srow, scol, wbuf, E_);
        repack_k<<<64, 256, 0, stream>>>(Whid + (size_t)l * 4 * 128 * 32, Wcat);
        gemm_k128<128, false, false><<<RT, 256, 0, stream>>>(bufA, Wcat, nullptr, bufB, N_);
        edge_agg2<128, 4, true><<<NW, 256, 0, stream>>>(bufB, wbuf, off, scol, bufA, N_);
    }

    // output GAT layer (single head, 64 classes, no activation)
    attn_scores<1><<<NW, 256, 0, stream>>>(bufA, aout, ssrc, sdst, N_);
    wexp_k<1><<<EB, 256, 0, stream>>>(ssrc, sdst, srow, scol, wbuf, E_);
    gemm_k128<64, false, false><<<RT, 256, 0, stream>>>(bufA, Wout, nullptr, bufB, N_);
    edge_agg2<64, 1, false><<<NW, 256, 0, stream>>>(bufB, wbuf, off, scol, out, N_);
}

// Round 3
// 932.939 us; speedup vs baseline: 1.3060x; 1.0582x over previous
//
#include <hip/hip_runtime.h>
#include <hip/hip_bf16.h>
#include <cstdint>
#include <cstddef>

#define LRELU_ALPHA 0.2f

// ---------------- CSR build ----------------

// histogram + per-edge rank (rank write is coalesced; atomic pays the serialization once)
__global__ void hist_k(const int* __restrict__ ei, int* __restrict__ counts,
                       int* __restrict__ rank, int E_) {
    int e = blockIdx.x * 256 + threadIdx.x;
    if (e < E_) {
        int r = ei[e];
        rank[e] = atomicAdd(&counts[r], 1);
    }
}

__global__ void scan_block_k(const int* __restrict__ counts, int* __restrict__ tmp,
                             int* __restrict__ bsum, int n) {
    __shared__ int s[256];
    int i = blockIdx.x * 256 + threadIdx.x;
    int v = (i < n) ? counts[i] : 0;
    s[threadIdx.x] = v;
    __syncthreads();
    for (int d = 1; d < 256; d <<= 1) {
        int t_ = (threadIdx.x >= d) ? s[threadIdx.x - d] : 0;
        __syncthreads();
        s[threadIdx.x] += t_;
        __syncthreads();
    }
    if (i < n) tmp[i] = s[threadIdx.x];
    if (threadIdx.x == 255) bsum[blockIdx.x] = s[255];
}

__global__ void scan_sums_k(int* bsum, int nb) {
    __shared__ int s[512];
    int v = ((int)threadIdx.x < nb) ? bsum[threadIdx.x] : 0;
    s[threadIdx.x] = v;
    __syncthreads();
    for (int d = 1; d < 512; d <<= 1) {
        int t_ = ((int)threadIdx.x >= d) ? s[threadIdx.x - d] : 0;
        __syncthreads();
        s[threadIdx.x] += t_;
        __syncthreads();
    }
    if ((int)threadIdx.x < nb) bsum[threadIdx.x] = s[threadIdx.x] - v;  // exclusive
}

__global__ void finalize_k(const int* __restrict__ tmp, const int* __restrict__ bsum,
                           int* __restrict__ off, int n) {
    int i = blockIdx.x * 256 + threadIdx.x;
    if (i < n) off[i + 1] = tmp[i] + bsum[blockIdx.x];
    if (i == 0) off[0] = 0;
}

// atomic-free scatter, single 4B payload
__global__ void scatter_k(const int* __restrict__ ei, const int* __restrict__ rank,
                          const int* __restrict__ off, int* __restrict__ scol, int E_) {
    int e = blockIdx.x * 256 + threadIdx.x;
    if (e < E_) {
        int r = ei[e];
        int pos = off[r] + rank[e];
        scol[pos] = ei[E_ + e];
    }
}

// W_hid[l] is [4][128][32]; repack to Wcat[k*128 + hd*32 + j]
__global__ void repack_k(const float* __restrict__ Wl, float* __restrict__ Wc) {
    int i = blockIdx.x * 256 + threadIdx.x;
    if (i < 128 * 128) {
        int k = i >> 7, c = i & 127;
        int hd = c >> 5, j = c & 31;
        Wc[i] = Wl[(hd * 128 + k) * 32 + j];
    }
}

// ---------------- GEMM: Y[n, 0:KJ] = act(X[n, 0:128] @ W[128, KJ] + bias) ----------------

template <int KJ, bool ELU_ACT, bool BIAS>
__global__ __launch_bounds__(256) void gemm_k128(const float* __restrict__ X,
                                                 const float* __restrict__ W,
                                                 const float* __restrict__ bias,
                                                 float* __restrict__ Y, int nRows) {
    constexpr int BK = 32;
    constexpr int XS = 132;
    constexpr int WS = KJ + 4;
    constexpr int MC = KJ / 16;
    __shared__ float sXT[BK * XS];
    __shared__ float sW[BK * WS];
    int t = threadIdx.x;
    int tc = t & 15, tr = t >> 4;
    int rowBase = blockIdx.x * 128;
    int r0 = tr * 8;
    int c0 = tc * MC;
    float acc[8][MC] = {};

    for (int kc = 0; kc < 128; kc += BK) {
        #pragma unroll
        for (int ii = 0; ii < 4; ii++) {
            int i = t + ii * 256;
            int r = i >> 3;
            int k4 = i & 7;
            int gr = rowBase + r;
            float4 v = make_float4(0.f, 0.f, 0.f, 0.f);
            if (gr < nRows) v = *(const float4*)&X[gr * 128 + kc + k4 * 4];
            sXT[(k4 * 4 + 0) * XS + r] = v.x;
            sXT[(k4 * 4 + 1) * XS + r] = v.y;
            sXT[(k4 * 4 + 2) * XS + r] = v.z;
            sXT[(k4 * 4 + 3) * XS + r] = v.w;
        }
        for (int i = t; i < BK * KJ / 4; i += 256) {
            int k = i / (KJ / 4);
            int c4 = i % (KJ / 4);
            float4 v = *(const float4*)&W[(kc + k) * KJ + c4 * 4];
            *(float4*)&sW[k * WS + c4 * 4] = v;
        }
        __syncthreads();
        #pragma unroll
        for (int k = 0; k < BK; k++) {
            float xv[8], wv[MC];
            *(float4*)&xv[0] = *(const float4*)&sXT[k * XS + r0];
            *(float4*)&xv[4] = *(const float4*)&sXT[k * XS + r0 + 4];
            #pragma unroll
            for (int c = 0; c < MC; c += 4)
                *(float4*)&wv[c] = *(const float4*)&sW[k * WS + c0 + c];
            #pragma unroll
            for (int rr = 0; rr < 8; rr++)
                #pragma unroll
                for (int cc = 0; cc < MC; cc++)
                    acc[rr][cc] = fmaf(xv[rr], wv[cc], acc[rr][cc]);
        }
        __syncthreads();
    }
    #pragma unroll
    for (int rr = 0; rr < 8; rr++) {
        int gr = rowBase + r0 + rr;
        if (gr < nRows) {
            #pragma unroll
            for (int cc = 0; cc < MC; cc += 4) {
                float4 v;
                float* vp = (float*)&v;
                #pragma unroll
                for (int q = 0; q < 4; q++) {
                    float val = acc[rr][cc + q];
                    if (BIAS) val += bias[c0 + cc + q];
                    if (ELU_ACT) val = val > 0.f ? val : (__expf(val) - 1.f);
                    vp[q] = val;
                }
                *(float4*)&Y[gr * KJ + c0 + cc] = v;
            }
        }
    }
}

// ---------------- attention scores ----------------

template <int H>
__global__ __launch_bounds__(256) void attn_scores(const float* __restrict__ h,
                                                   const float* __restrict__ a,
                                                   float* __restrict__ s_src,
                                                   float* __restrict__ s_dst, int n) {
    __shared__ float sa[H * 2 * 128];
    for (int i = threadIdx.x; i < H * 2 * 128; i += 256) sa[i] = a[i];
    __syncthreads();
    int lane = threadIdx.x & 63, wv = threadIdx.x >> 6;
    int node = blockIdx.x * 4 + wv;
    if (node >= n) return;
    float h0 = h[node * 128 + lane];
    float h1 = h[node * 128 + 64 + lane];
    #pragma unroll
    for (int hd = 0; hd < H; hd++) {
        #pragma unroll
        for (int side = 0; side < 2; side++) {
            const float* av = &sa[(hd * 2 + side) * 128];
            float p = h0 * av[lane] + h1 * av[64 + lane];
            #pragma unroll
            for (int s = 32; s > 0; s >>= 1) p += __shfl_xor(p, s);
            if (lane == 0) {
                float* dst = side ? s_dst : s_src;
                dst[node * H + hd] = p;
            }
        }
    }
}

// ---------------- fused edge pass: w = exp(lrelu(ssrc[r]+sdst[c])); out[r] = sum w*hW[c] / sum w --------
// one wave per destination row; lane = feature; weights computed in-lane (no max pass:
// |logit| <= ~8 by construction so fp32 exp is safe; per-head denom identical across the
// head's lanes so no cross-lane reduction needed). Unroll x8 batches loads for MLP.

template <int DHT, int H, bool ELU_ACT>
__global__ __launch_bounds__(256) void edge_agg3(const float* __restrict__ hW,
                                                 const float* __restrict__ ssrc,
                                                 const float* __restrict__ sdst,
                                                 const int* __restrict__ off,
                                                 const int* __restrict__ scol,
                                                 float* __restrict__ out, int nRows) {
    constexpr int FPL = DHT / 64;  // features per lane
    constexpr int UN = 8;
    int lane = threadIdx.x & 63;
    int wv = threadIdx.x >> 6;
    int r = blockIdx.x * 4 + wv;
    if (r >= nRows) return;
    int begin = off[r], end = off[r + 1];
    bool lo = (lane & 32) == 0;

    // per-lane source score (head of feature p*64+lane)
    float ssl[FPL];
    if (H == 4) {
        float4 a = *(const float4*)&ssrc[r * 4];
        ssl[0] = lo ? a.x : a.y;
        if (FPL == 2) ssl[1] = lo ? a.z : a.w;
    } else {
        float a = ssrc[r];
        #pragma unroll
        for (int p = 0; p < FPL; p++) ssl[p] = a;
    }

    float acc[FPL] = {};
    float den[FPL] = {};

    int i = begin;
    for (; i + UN <= end; i += UN) {
        int c[UN];
        #pragma unroll
        for (int j = 0; j < UN; j++) c[j] = scol[i + j];
        float sd[UN][FPL];
        #pragma unroll
        for (int j = 0; j < UN; j++) {
            if (H == 4) {
                float4 q = *(const float4*)&sdst[(size_t)c[j] * 4];
                sd[j][0] = lo ? q.x : q.y;
                if (FPL == 2) sd[j][1] = lo ? q.z : q.w;
            } else {
                float q = sdst[c[j]];
                #pragma unroll
                for (int p = 0; p < FPL; p++) sd[j][p] = q;
            }
        }
        float hv[UN][FPL];
        #pragma unroll
        for (int j = 0; j < UN; j++)
            #pragma unroll
            for (int p = 0; p < FPL; p++)
                hv[j][p] = hW[(size_t)c[j] * DHT + p * 64 + lane];
        #pragma unroll
        for (int j = 0; j < UN; j++)
            #pragma unroll
            for (int p = 0; p < FPL; p++) {
                float lg = ssl[p] + sd[j][p];
                lg = lg > 0.f ? lg : LRELU_ALPHA * lg;
                float w = __expf(lg);
                den[p] += w;
                acc[p] = fmaf(w, hv[j][p], acc[p]);
            }
    }
    for (; i < end; i++) {
        int c = scol[i];
        float sd[FPL];
        if (H == 4) {
            float4 q = *(const float4*)&sdst[(size_t)c * 4];
            sd[0] = lo ? q.x : q.y;
            if (FPL == 2) sd[1] = lo ? q.z : q.w;
        } else {
            float q = sdst[c];
            #pragma unroll
            for (int p = 0; p < FPL; p++) sd[p] = q;
        }
        #pragma unroll
        for (int p = 0; p < FPL; p++) {
            float lg = ssl[p] + sd[p];
            lg = lg > 0.f ? lg : LRELU_ALPHA * lg;
            float w = __expf(lg);
            den[p] += w;
            acc[p] = fmaf(w, hW[(size_t)c * DHT + p * 64 + lane], acc[p]);
        }
    }

    #pragma unroll
    for (int p = 0; p < FPL; p++) {
        float v = den[p] > 0.f ? acc[p] / den[p] : 0.f;
        if (ELU_ACT) v = v > 0.f ? v : (__expf(v) - 1.f);
        out[(size_t)r * DHT + p * 64 + lane] = v;
    }
}

// ---------------- launcher ----------------

extern "C" void kernel_launch(void* const* d_in, const int* in_sizes, int n_in,
                              void* d_out, int out_size, void* d_ws, size_t ws_size,
                              hipStream_t stream) {
    const float* x    = (const float*)d_in[0];
    const int*   ei   = (const int*)d_in[1];
    const float* Win  = (const float*)d_in[2];
    const float* bin  = (const float*)d_in[3];
    const float* ahid = (const float*)d_in[4];
    const float* Whid = (const float*)d_in[5];
    const float* aout = (const float*)d_in[6];
    const float* Wout = (const float*)d_in[7];
    float* out = (float*)d_out;

    const int N_ = in_sizes[0] / 128;
    const int E_ = in_sizes[1] / 2;

    char* p = (char*)d_ws;
    auto alloc = [&](size_t bytes) {
        char* q = p;
        p += (bytes + 511) & ~(size_t)511;
        return q;
    };
    int* counts = (int*)alloc((size_t)N_ * 4);
    int* tmp    = (int*)alloc((size_t)N_ * 4);
    int* rank   = (int*)alloc((size_t)E_ * 4);
    int* off    = (int*)alloc((size_t)(N_ + 1) * 4);
    int* bsum   = (int*)alloc(4096);
    int* scol   = (int*)alloc((size_t)E_ * 4);
    float* ssrc = (float*)alloc((size_t)N_ * 4 * 4);
    float* sdst = (float*)alloc((size_t)N_ * 4 * 4);
    float* bufA = (float*)alloc((size_t)N_ * 128 * 4);
    float* bufB = (float*)alloc((size_t)N_ * 128 * 4);
    float* Wcat = (float*)alloc(128 * 128 * 4);

    int NB = (N_ + 255) / 256;
    int EB = (E_ + 255) / 256;
    int RT = (N_ + 127) / 128;
    int NW = (N_ + 3) / 4;

    // CSR by destination (= edge_index[0], the softmax segment key)
    hipMemsetAsync(counts, 0, (size_t)N_ * 4, stream);
    hist_k<<<EB, 256, 0, stream>>>(ei, counts, rank, E_);
    scan_block_k<<<NB, 256, 0, stream>>>(counts, tmp, bsum, N_);
    scan_sums_k<<<1, 512, 0, stream>>>(bsum, NB);
    finalize_k<<<NB, 256, 0, stream>>>(tmp, bsum, off, N_);
    scatter_k<<<EB, 256, 0, stream>>>(ei, rank, off, scol, E_);

    // input linear + ELU
    gemm_k128<128, true, true><<<RT, 256, 0, stream>>>(x, Win, bin, bufA, N_);

    // hidden GAT layers
    for (int l = 0; l < 2; l++) {
        attn_scores<4><<<NW, 256, 0, stream>>>(bufA, ahid + (size_t)l * 4 * 2 * 128, ssrc, sdst, N_);
        repack_k<<<64, 256, 0, stream>>>(Whid + (size_t)l * 4 * 128 * 32, Wcat);
        gemm_k128<128, false, false><<<RT, 256, 0, stream>>>(bufA, Wcat, nullptr, bufB, N_);
        edge_agg3<128, 4, true><<<NW, 256, 0, stream>>>(bufB, ssrc, sdst, off, scol, bufA, N_);
    }

    // output GAT layer (single head, 64 classes, no activation)
    attn_scores<1><<<NW, 256, 0, stream>>>(bufA, aout, ssrc, sdst, N_);
    gemm_k128<64, false, false><<<RT, 256, 0, stream>>>(bufA, Wout, nullptr, bufB, N_);
    edge_agg3<64, 1, false><<<NW, 256, 0, stream>>>(bufB, ssrc, sdst, off, scol, out, N_);
}

// Round 4
// 792.082 us; speedup vs baseline: 1.5382x; 1.1778x over previous
//
#include <hip/hip_runtime.h>
#include <hip/hip_bf16.h>
#include <cstdint>
#include <cstddef>

#define LRELU_ALPHA 0.2f

__device__ __forceinline__ unsigned short f2bf(float f) {
    unsigned int u = __float_as_uint(f);
    unsigned int r = (u + 0x7fffu + ((u >> 16) & 1u)) >> 16;   // RTN-even
    return (unsigned short)r;
}
__device__ __forceinline__ float bf2f(unsigned int lo16) {
    return __uint_as_float(lo16 << 16);
}

// ---------------- CSR build ----------------

__global__ void hist_k(const int* __restrict__ ei, int* __restrict__ counts,
                       int* __restrict__ rank, int E_) {
    int e = blockIdx.x * 256 + threadIdx.x;
    if (e < E_) {
        int r = ei[e];
        rank[e] = atomicAdd(&counts[r], 1);
    }
}

__global__ void scan_block_k(const int* __restrict__ counts, int* __restrict__ tmp,
                             int* __restrict__ bsum, int n) {
    __shared__ int s[256];
    int i = blockIdx.x * 256 + threadIdx.x;
    int v = (i < n) ? counts[i] : 0;
    s[threadIdx.x] = v;
    __syncthreads();
    for (int d = 1; d < 256; d <<= 1) {
        int t_ = (threadIdx.x >= d) ? s[threadIdx.x - d] : 0;
        __syncthreads();
        s[threadIdx.x] += t_;
        __syncthreads();
    }
    if (i < n) tmp[i] = s[threadIdx.x];
    if (threadIdx.x == 255) bsum[blockIdx.x] = s[255];
}

__global__ void scan_sums_k(int* bsum, int nb) {
    __shared__ int s[512];
    int v = ((int)threadIdx.x < nb) ? bsum[threadIdx.x] : 0;
    s[threadIdx.x] = v;
    __syncthreads();
    for (int d = 1; d < 512; d <<= 1) {
        int t_ = ((int)threadIdx.x >= d) ? s[threadIdx.x - d] : 0;
        __syncthreads();
        s[threadIdx.x] += t_;
        __syncthreads();
    }
    if ((int)threadIdx.x < nb) bsum[threadIdx.x] = s[threadIdx.x] - v;  // exclusive
}

__global__ void finalize_k(const int* __restrict__ tmp, const int* __restrict__ bsum,
                           int* __restrict__ off, int n) {
    int i = blockIdx.x * 256 + threadIdx.x;
    if (i < n) off[i + 1] = tmp[i] + bsum[blockIdx.x];
    if (i == 0) off[0] = 0;
}

__global__ void scatter_k(const int* __restrict__ ei, const int* __restrict__ rank,
                          const int* __restrict__ off, int* __restrict__ scol, int E_) {
    int e = blockIdx.x * 256 + threadIdx.x;
    if (e < E_) {
        int r = ei[e];
        int pos = off[r] + rank[e];
        scol[pos] = ei[E_ + e];
    }
}

// W_hid[l] is [4][128][32]; repack to Wcat[k*128 + hd*32 + j]
__global__ void repack_k(const float* __restrict__ Wl, float* __restrict__ Wc) {
    int i = blockIdx.x * 256 + threadIdx.x;
    if (i < 128 * 128) {
        int k = i >> 7, c = i & 127;
        int hd = c >> 5, j = c & 31;
        Wc[i] = Wl[(hd * 128 + k) * 32 + j];
    }
}

// ---------------- GEMM: Y[n, 0:KJ] = act(X[n, 0:128] @ W[128, KJ] + bias) ----------------
// BF16_OUT: write Y as packed bf16 row-major (KJ cols * 2B).

template <int KJ, bool ELU_ACT, bool BIAS, bool BF16_OUT>
__global__ __launch_bounds__(256) void gemm_k128(const float* __restrict__ X,
                                                 const float* __restrict__ W,
                                                 const float* __restrict__ bias,
                                                 void* __restrict__ Yv, int nRows) {
    constexpr int BK = 32;
    constexpr int XS = 132;
    constexpr int WS = KJ + 4;
    constexpr int MC = KJ / 16;
    __shared__ float sXT[BK * XS];
    __shared__ float sW[BK * WS];
    int t = threadIdx.x;
    int tc = t & 15, tr = t >> 4;
    int rowBase = blockIdx.x * 128;
    int r0 = tr * 8;
    int c0 = tc * MC;
    float acc[8][MC] = {};

    for (int kc = 0; kc < 128; kc += BK) {
        #pragma unroll
        for (int ii = 0; ii < 4; ii++) {
            int i = t + ii * 256;
            int r = i >> 3;
            int k4 = i & 7;
            int gr = rowBase + r;
            float4 v = make_float4(0.f, 0.f, 0.f, 0.f);
            if (gr < nRows) v = *(const float4*)&X[gr * 128 + kc + k4 * 4];
            sXT[(k4 * 4 + 0) * XS + r] = v.x;
            sXT[(k4 * 4 + 1) * XS + r] = v.y;
            sXT[(k4 * 4 + 2) * XS + r] = v.z;
            sXT[(k4 * 4 + 3) * XS + r] = v.w;
        }
        for (int i = t; i < BK * KJ / 4; i += 256) {
            int k = i / (KJ / 4);
            int c4 = i % (KJ / 4);
            float4 v = *(const float4*)&W[(kc + k) * KJ + c4 * 4];
            *(float4*)&sW[k * WS + c4 * 4] = v;
        }
        __syncthreads();
        #pragma unroll
        for (int k = 0; k < BK; k++) {
            float xv[8], wv[MC];
            *(float4*)&xv[0] = *(const float4*)&sXT[k * XS + r0];
            *(float4*)&xv[4] = *(const float4*)&sXT[k * XS + r0 + 4];
            #pragma unroll
            for (int c = 0; c < MC; c += 4)
                *(float4*)&wv[c] = *(const float4*)&sW[k * WS + c0 + c];
            #pragma unroll
            for (int rr = 0; rr < 8; rr++)
                #pragma unroll
                for (int cc = 0; cc < MC; cc++)
                    acc[rr][cc] = fmaf(xv[rr], wv[cc], acc[rr][cc]);
        }
        __syncthreads();
    }
    #pragma unroll
    for (int rr = 0; rr < 8; rr++) {
        int gr = rowBase + r0 + rr;
        if (gr >= nRows) continue;
        float val[MC];
        #pragma unroll
        for (int cc = 0; cc < MC; cc++) {
            float v = acc[rr][cc];
            if (BIAS) v += bias[c0 + cc];
            if (ELU_ACT) v = v > 0.f ? v : (__expf(v) - 1.f);
            val[cc] = v;
        }
        if (BF16_OUT) {
            unsigned int pk[MC / 2];
            #pragma unroll
            for (int q = 0; q < MC / 2; q++)
                pk[q] = (unsigned int)f2bf(val[2 * q]) | ((unsigned int)f2bf(val[2 * q + 1]) << 16);
            unsigned int* Y = (unsigned int*)Yv;
            #pragma unroll
            for (int q = 0; q < MC / 2; q += 4)
                *(uint4*)&Y[(size_t)gr * (KJ / 2) + c0 / 2 + q] = *(uint4*)&pk[q];
        } else {
            float* Y = (float*)Yv;
            #pragma unroll
            for (int cc = 0; cc < MC; cc += 4)
                *(float4*)&Y[(size_t)gr * KJ + c0 + cc] = *(float4*)&val[cc];
        }
    }
}

// ---------------- attention scores ----------------

template <int H>
__global__ __launch_bounds__(256) void attn_scores(const float* __restrict__ h,
                                                   const float* __restrict__ a,
                                                   float* __restrict__ s_src,
                                                   float* __restrict__ s_dst, int n) {
    __shared__ float sa[H * 2 * 128];
    for (int i = threadIdx.x; i < H * 2 * 128; i += 256) sa[i] = a[i];
    __syncthreads();
    int lane = threadIdx.x & 63, wv = threadIdx.x >> 6;
    int node = blockIdx.x * 4 + wv;
    if (node >= n) return;
    float h0 = h[node * 128 + lane];
    float h1 = h[node * 128 + 64 + lane];
    #pragma unroll
    for (int hd = 0; hd < H; hd++) {
        #pragma unroll
        for (int side = 0; side < 2; side++) {
            const float* av = &sa[(hd * 2 + side) * 128];
            float p = h0 * av[lane] + h1 * av[64 + lane];
            #pragma unroll
            for (int s = 32; s > 0; s >>= 1) p += __shfl_xor(p, s);
            if (lane == 0) {
                float* dst = side ? s_dst : s_src;
                dst[node * H + hd] = p;
            }
        }
    }
}

// ---------------- hidden edge pass (bf16 hW, 4 heads) ----------------
// one wave per dst row; lane owns features (2*lane, 2*lane+1), head = lane>>4.
// w = exp(lrelu(ssrc+sdst)) computed in-lane; no max-subtraction (|logit| small).

template <bool ELU_ACT>
__global__ __launch_bounds__(256) void edge_agg_bf(const unsigned int* __restrict__ hW2,
                                                   const float* __restrict__ ssrc,
                                                   const float* __restrict__ sdst,
                                                   const int* __restrict__ off,
                                                   const int* __restrict__ scol,
                                                   float* __restrict__ out, int nRows) {
    constexpr int UN = 8;
    int lane = threadIdx.x & 63;
    int wv = threadIdx.x >> 6;
    int r = blockIdx.x * 4 + wv;
    if (r >= nRows) return;
    int begin = off[r], end = off[r + 1];
    int hd = lane >> 4;

    float ssl = ssrc[r * 4 + hd];
    float acc0 = 0.f, acc1 = 0.f, den = 0.f;

    int i = begin;
    for (; i + UN <= end; i += UN) {
        int c[UN];
        #pragma unroll
        for (int j = 0; j < UN; j++) c[j] = scol[i + j];
        float sd[UN];
        #pragma unroll
        for (int j = 0; j < UN; j++) sd[j] = sdst[(size_t)c[j] * 4 + hd];
        unsigned int hv[UN];
        #pragma unroll
        for (int j = 0; j < UN; j++) hv[j] = hW2[(size_t)c[j] * 64 + lane];
        #pragma unroll
        for (int j = 0; j < UN; j++) {
            float lg = ssl + sd[j];
            lg = lg > 0.f ? lg : LRELU_ALPHA * lg;
            float w = __expf(lg);
            den += w;
            acc0 = fmaf(w, bf2f(hv[j] & 0xffffu), acc0);
            acc1 = fmaf(w, bf2f(hv[j] >> 16), acc1);
        }
    }
    for (; i < end; i++) {
        int c = scol[i];
        float sd = sdst[(size_t)c * 4 + hd];
        unsigned int hv = hW2[(size_t)c * 64 + lane];
        float lg = ssl + sd;
        lg = lg > 0.f ? lg : LRELU_ALPHA * lg;
        float w = __expf(lg);
        den += w;
        acc0 = fmaf(w, bf2f(hv & 0xffffu), acc0);
        acc1 = fmaf(w, bf2f(hv >> 16), acc1);
    }

    float inv = den > 0.f ? 1.f / den : 0.f;
    float v0 = acc0 * inv, v1 = acc1 * inv;
    if (ELU_ACT) {
        v0 = v0 > 0.f ? v0 : (__expf(v0) - 1.f);
        v1 = v1 > 0.f ? v1 : (__expf(v1) - 1.f);
    }
    *(float2*)&out[(size_t)r * 128 + 2 * lane] = make_float2(v0, v1);
}

// ---------------- final edge pass (fp32 hW, 1 head, 64 cols) ----------------

__global__ __launch_bounds__(256) void edge_agg_f(const float* __restrict__ hW,
                                                  const float* __restrict__ ssrc,
                                                  const float* __restrict__ sdst,
                                                  const int* __restrict__ off,
                                                  const int* __restrict__ scol,
                                                  float* __restrict__ out, int nRows) {
    constexpr int UN = 8;
    int lane = threadIdx.x & 63;
    int wv = threadIdx.x >> 6;
    int r = blockIdx.x * 4 + wv;
    if (r >= nRows) return;
    int begin = off[r], end = off[r + 1];

    float ssl = ssrc[r];
    float acc = 0.f, den = 0.f;

    int i = begin;
    for (; i + UN <= end; i += UN) {
        int c[UN];
        #pragma unroll
        for (int j = 0; j < UN; j++) c[j] = scol[i + j];
        float sd[UN];
        #pragma unroll
        for (int j = 0; j < UN; j++) sd[j] = sdst[c[j]];
        float hv[UN];
        #pragma unroll
        for (int j = 0; j < UN; j++) hv[j] = hW[(size_t)c[j] * 64 + lane];
        #pragma unroll
        for (int j = 0; j < UN; j++) {
            float lg = ssl + sd[j];
            lg = lg > 0.f ? lg : LRELU_ALPHA * lg;
            float w = __expf(lg);
            den += w;
            acc = fmaf(w, hv[j], acc);
        }
    }
    for (; i < end; i++) {
        int c = scol[i];
        float sd = sdst[c];
        float lg = ssl + sd;
        lg = lg > 0.f ? lg : LRELU_ALPHA * lg;
        float w = __expf(lg);
        den += w;
        acc = fmaf(w, hW[(size_t)c * 64 + lane], acc);
    }

    out[(size_t)r * 64 + lane] = den > 0.f ? acc / den : 0.f;
}

// ---------------- launcher ----------------

extern "C" void kernel_launch(void* const* d_in, const int* in_sizes, int n_in,
                              void* d_out, int out_size, void* d_ws, size_t ws_size,
                              hipStream_t stream) {
    const float* x    = (const float*)d_in[0];
    const int*   ei   = (const int*)d_in[1];
    const float* Win  = (const float*)d_in[2];
    const float* bin  = (const float*)d_in[3];
    const float* ahid = (const float*)d_in[4];
    const float* Whid = (const float*)d_in[5];
    const float* aout = (const float*)d_in[6];
    const float* Wout = (const float*)d_in[7];
    float* out = (float*)d_out;

    const int N_ = in_sizes[0] / 128;
    const int E_ = in_sizes[1] / 2;

    char* p = (char*)d_ws;
    auto alloc = [&](size_t bytes) {
        char* q = p;
        p += (bytes + 511) & ~(size_t)511;
        return q;
    };
    int* counts = (int*)alloc((size_t)N_ * 4);
    int* tmp    = (int*)alloc((size_t)N_ * 4);
    int* rank   = (int*)alloc((size_t)E_ * 4);
    int* off    = (int*)alloc((size_t)(N_ + 1) * 4);
    int* bsum   = (int*)alloc(4096);
    int* scol   = (int*)alloc((size_t)E_ * 4);
    float* ssrc = (float*)alloc((size_t)N_ * 4 * 4);
    float* sdst = (float*)alloc((size_t)N_ * 4 * 4);
    float* bufA = (float*)alloc((size_t)N_ * 128 * 4);   // h (fp32)
    unsigned int* hWb = (unsigned int*)alloc((size_t)N_ * 64 * 4);  // hW bf16 packed
    float* bufB = (float*)alloc((size_t)N_ * 64 * 4);    // final hW (fp32)
    float* Wcat = (float*)alloc(128 * 128 * 4);

    int NB = (N_ + 255) / 256;
    int EB = (E_ + 255) / 256;
    int RT = (N_ + 127) / 128;
    int NW = (N_ + 3) / 4;

    // CSR by destination (= edge_index[0], the softmax segment key)
    hipMemsetAsync(counts, 0, (size_t)N_ * 4, stream);
    hist_k<<<EB, 256, 0, stream>>>(ei, counts, rank, E_);
    scan_block_k<<<NB, 256, 0, stream>>>(counts, tmp, bsum, N_);
    scan_sums_k<<<1, 512, 0, stream>>>(bsum, NB);
    finalize_k<<<NB, 256, 0, stream>>>(tmp, bsum, off, N_);
    scatter_k<<<EB, 256, 0, stream>>>(ei, rank, off, scol, E_);

    // input linear + ELU (fp32 out)
    gemm_k128<128, true, true, false><<<RT, 256, 0, stream>>>(x, Win, bin, bufA, N_);

    // hidden GAT layers
    for (int l = 0; l < 2; l++) {
        attn_scores<4><<<NW, 256, 0, stream>>>(bufA, ahid + (size_t)l * 4 * 2 * 128, ssrc, sdst, N_);
        repack_k<<<64, 256, 0, stream>>>(Whid + (size_t)l * 4 * 128 * 32, Wcat);
        gemm_k128<128, false, false, true><<<RT, 256, 0, stream>>>(bufA, Wcat, nullptr, hWb, N_);
        edge_agg_bf<true><<<NW, 256, 0, stream>>>(hWb, ssrc, sdst, off, scol, bufA, N_);
    }

    // output GAT layer (single head, 64 classes, no activation)
    attn_scores<1><<<NW, 256, 0, stream>>>(bufA, aout, ssrc, sdst, N_);
    gemm_k128<64, false, false, false><<<RT, 256, 0, stream>>>(bufA, Wout, nullptr, bufB, N_);
    edge_agg_f<<<NW, 256, 0, stream>>>(bufB, ssrc, sdst, off, scol, out, N_);
}

// Round 5
// 746.500 us; speedup vs baseline: 1.6321x; 1.0611x over previous
//
#include <hip/hip_runtime.h>
#include <hip/hip_bf16.h>
#include <cstdint>
#include <cstddef>

#define LRELU_ALPHA 0.2f

__device__ __forceinline__ unsigned short f2bf(float f) {
    unsigned int u = __float_as_uint(f);
    unsigned int r = (u + 0x7fffu + ((u >> 16) & 1u)) >> 16;   // RTN-even
    return (unsigned short)r;
}
__device__ __forceinline__ float bf2f(unsigned int lo16) {
    return __uint_as_float(lo16 << 16);
}

// ---------------- CSR build ----------------

__global__ void hist_k(const int* __restrict__ ei, int* __restrict__ counts,
                       int* __restrict__ rank, int E_) {
    int e = blockIdx.x * 256 + threadIdx.x;
    if (e < E_) {
        int r = ei[e];
        rank[e] = atomicAdd(&counts[r], 1);
    }
}

__global__ void scan_block_k(const int* __restrict__ counts, int* __restrict__ tmp,
                             int* __restrict__ bsum, int n) {
    __shared__ int s[256];
    int i = blockIdx.x * 256 + threadIdx.x;
    int v = (i < n) ? counts[i] : 0;
    s[threadIdx.x] = v;
    __syncthreads();
    for (int d = 1; d < 256; d <<= 1) {
        int t_ = (threadIdx.x >= d) ? s[threadIdx.x - d] : 0;
        __syncthreads();
        s[threadIdx.x] += t_;
        __syncthreads();
    }
    if (i < n) tmp[i] = s[threadIdx.x];
    if (threadIdx.x == 255) bsum[blockIdx.x] = s[255];
}

__global__ void scan_sums_k(int* bsum, int nb) {
    __shared__ int s[512];
    int v = ((int)threadIdx.x < nb) ? bsum[threadIdx.x] : 0;
    s[threadIdx.x] = v;
    __syncthreads();
    for (int d = 1; d < 512; d <<= 1) {
        int t_ = ((int)threadIdx.x >= d) ? s[threadIdx.x - d] : 0;
        __syncthreads();
        s[threadIdx.x] += t_;
        __syncthreads();
    }
    if ((int)threadIdx.x < nb) bsum[threadIdx.x] = s[threadIdx.x] - v;  // exclusive
}

__global__ void finalize_k(const int* __restrict__ tmp, const int* __restrict__ bsum,
                           int* __restrict__ off, int n) {
    int i = blockIdx.x * 256 + threadIdx.x;
    if (i < n) off[i + 1] = tmp[i] + bsum[blockIdx.x];
    if (i == 0) off[0] = 0;
}

__global__ void scatter_k(const int* __restrict__ ei, const int* __restrict__ rank,
                          const int* __restrict__ off, int* __restrict__ scol, int E_) {
    int e = blockIdx.x * 256 + threadIdx.x;
    if (e < E_) {
        int r = ei[e];
        int pos = off[r] + rank[e];
        scol[pos] = ei[E_ + e];
    }
}

// W_hid[l] is [4][128][32]; repack to Wcat[k*128 + hd*32 + j]
__global__ void repack_k(const float* __restrict__ Wl, float* __restrict__ Wc) {
    int i = blockIdx.x * 256 + threadIdx.x;
    if (i < 128 * 128) {
        int k = i >> 7, c = i & 127;
        int hd = c >> 5, j = c & 31;
        Wc[i] = Wl[(hd * 128 + k) * 32 + j];
    }
}

// ---------------- GEMM: Y[n, 0:KJ] = act(X[n, 0:128] @ W[128, KJ] + bias) ----------------
// BF16_OUT: write Y as packed bf16 row-major (KJ cols * 2B).

template <int KJ, bool ELU_ACT, bool BIAS, bool BF16_OUT>
__global__ __launch_bounds__(256) void gemm_k128(const float* __restrict__ X,
                                                 const float* __restrict__ W,
                                                 const float* __restrict__ bias,
                                                 void* __restrict__ Yv, int nRows) {
    constexpr int BK = 32;
    constexpr int XS = 132;
    constexpr int WS = KJ + 4;
    constexpr int MC = KJ / 16;
    __shared__ float sXT[BK * XS];
    __shared__ float sW[BK * WS];
    int t = threadIdx.x;
    int tc = t & 15, tr = t >> 4;
    int rowBase = blockIdx.x * 128;
    int r0 = tr * 8;
    int c0 = tc * MC;
    float acc[8][MC] = {};

    for (int kc = 0; kc < 128; kc += BK) {
        #pragma unroll
        for (int ii = 0; ii < 4; ii++) {
            int i = t + ii * 256;
            int r = i >> 3;
            int k4 = i & 7;
            int gr = rowBase + r;
            float4 v = make_float4(0.f, 0.f, 0.f, 0.f);
            if (gr < nRows) v = *(const float4*)&X[gr * 128 + kc + k4 * 4];
            sXT[(k4 * 4 + 0) * XS + r] = v.x;
            sXT[(k4 * 4 + 1) * XS + r] = v.y;
            sXT[(k4 * 4 + 2) * XS + r] = v.z;
            sXT[(k4 * 4 + 3) * XS + r] = v.w;
        }
        for (int i = t; i < BK * KJ / 4; i += 256) {
            int k = i / (KJ / 4);
            int c4 = i % (KJ / 4);
            float4 v = *(const float4*)&W[(kc + k) * KJ + c4 * 4];
            *(float4*)&sW[k * WS + c4 * 4] = v;
        }
        __syncthreads();
        #pragma unroll
        for (int k = 0; k < BK; k++) {
            float xv[8], wv[MC];
            *(float4*)&xv[0] = *(const float4*)&sXT[k * XS + r0];
            *(float4*)&xv[4] = *(const float4*)&sXT[k * XS + r0 + 4];
            #pragma unroll
            for (int c = 0; c < MC; c += 4)
                *(float4*)&wv[c] = *(const float4*)&sW[k * WS + c0 + c];
            #pragma unroll
            for (int rr = 0; rr < 8; rr++)
                #pragma unroll
                for (int cc = 0; cc < MC; cc++)
                    acc[rr][cc] = fmaf(xv[rr], wv[cc], acc[rr][cc]);
        }
        __syncthreads();
    }
    #pragma unroll
    for (int rr = 0; rr < 8; rr++) {
        int gr = rowBase + r0 + rr;
        if (gr >= nRows) continue;
        float val[MC];
        #pragma unroll
        for (int cc = 0; cc < MC; cc++) {
            float v = acc[rr][cc];
            if (BIAS) v += bias[c0 + cc];
            if (ELU_ACT) v = v > 0.f ? v : (__expf(v) - 1.f);
            val[cc] = v;
        }
        if (BF16_OUT) {
            unsigned int pk[MC / 2];
            #pragma unroll
            for (int q = 0; q < MC / 2; q++)
                pk[q] = (unsigned int)f2bf(val[2 * q]) | ((unsigned int)f2bf(val[2 * q + 1]) << 16);
            unsigned int* Y = (unsigned int*)Yv;
            if (MC / 2 == 4) {
                *(uint4*)&Y[(size_t)gr * (KJ / 2) + c0 / 2] = *(uint4*)&pk[0];
            } else {
                *(uint2*)&Y[(size_t)gr * (KJ / 2) + c0 / 2] = *(uint2*)&pk[0];
            }
        } else {
            float* Y = (float*)Yv;
            #pragma unroll
            for (int cc = 0; cc < MC; cc += 4)
                *(float4*)&Y[(size_t)gr * KJ + c0 + cc] = *(float4*)&val[cc];
        }
    }
}

// ---------------- attention scores ----------------

template <int H>
__global__ __launch_bounds__(256) void attn_scores(const float* __restrict__ h,
                                                   const float* __restrict__ a,
                                                   float* __restrict__ s_src,
                                                   float* __restrict__ s_dst, int n) {
    __shared__ float sa[H * 2 * 128];
    for (int i = threadIdx.x; i < H * 2 * 128; i += 256) sa[i] = a[i];
    __syncthreads();
    int lane = threadIdx.x & 63, wv = threadIdx.x >> 6;
    int node = blockIdx.x * 4 + wv;
    if (node >= n) return;
    float h0 = h[node * 128 + lane];
    float h1 = h[node * 128 + 64 + lane];
    #pragma unroll
    for (int hd = 0; hd < H; hd++) {
        #pragma unroll
        for (int side = 0; side < 2; side++) {
            const float* av = &sa[(hd * 2 + side) * 128];
            float p = h0 * av[lane] + h1 * av[64 + lane];
            #pragma unroll
            for (int s = 32; s > 0; s >>= 1) p += __shfl_xor(p, s);
            if (lane == 0) {
                float* dst = side ? s_dst : s_src;
                dst[node * H + hd] = p;
            }
        }
    }
}

// ---------------- vectorized edge pass (bf16 hW rows) ----------------
// One wave per dst row. 16 lanes per row-slice; 4 edge slots (g = lane>>4) run
// concurrently; each lane loads FPL features of its slot's edge as packed bf16.
// Tail edges predicated (w=0). Slots combined by shfl_xor(16|32) at the end;
// slot g writes its quarter of the lane's features. No softmax max-pass
// (|logit| small by construction, fp32 exp safe).

template <int DHT, int H, bool ELU_ACT>
__global__ __launch_bounds__(256) void edge_agg_v(const unsigned int* __restrict__ hW2,
                                                  const float* __restrict__ ssrc,
                                                  const float* __restrict__ sdst,
                                                  const int* __restrict__ off,
                                                  const int* __restrict__ scol,
                                                  float* __restrict__ out, int nRows) {
    constexpr int FPL = DHT / 16;   // features per lane: 8 (hidden) or 4 (final)
    constexpr int UPL = FPL / 2;    // packed uints per lane: 4 or 2
    int lane = threadIdx.x & 63;
    int sub = lane & 15;
    int g = lane >> 4;
    int wv = threadIdx.x >> 6;
    int r = __builtin_amdgcn_readfirstlane(blockIdx.x * 4 + wv);
    if (r >= nRows) return;
    int begin = off[r], end = off[r + 1];

    int head = (H == 4) ? (sub >> 2) : 0;   // 8 feats/lane, 32 feats/head
    float ssl = ssrc[r * H + head];

    float acc[FPL] = {};
    float den = 0.f;

    for (int i = begin; i < end; i += 8) {
        int iA = i + g, iB = i + 4 + g;
        bool vA = iA < end, vB = iB < end;
        int cA = scol[vA ? iA : begin];
        int cB = scol[vB ? iB : begin];
        float sdA = sdst[cA * H + head];
        float sdB = sdst[cB * H + head];
        unsigned int hA[UPL], hB[UPL];
        int oA = cA * (DHT / 2) + sub * UPL;
        int oB = cB * (DHT / 2) + sub * UPL;
        if (UPL == 4) {
            *(uint4*)hA = *(const uint4*)&hW2[oA];
            *(uint4*)hB = *(const uint4*)&hW2[oB];
        } else {
            *(uint2*)hA = *(const uint2*)&hW2[oA];
            *(uint2*)hB = *(const uint2*)&hW2[oB];
        }
        float lgA = ssl + sdA; lgA = lgA > 0.f ? lgA : LRELU_ALPHA * lgA;
        float wA = vA ? __expf(lgA) : 0.f;
        float lgB = ssl + sdB; lgB = lgB > 0.f ? lgB : LRELU_ALPHA * lgB;
        float wB = vB ? __expf(lgB) : 0.f;
        den += wA + wB;
        #pragma unroll
        for (int q = 0; q < UPL; q++) {
            acc[2 * q]     = fmaf(wA, bf2f(hA[q] & 0xffffu), acc[2 * q]);
            acc[2 * q + 1] = fmaf(wA, bf2f(hA[q] >> 16),     acc[2 * q + 1]);
            acc[2 * q]     = fmaf(wB, bf2f(hB[q] & 0xffffu), acc[2 * q]);
            acc[2 * q + 1] = fmaf(wB, bf2f(hB[q] >> 16),     acc[2 * q + 1]);
        }
    }

    // combine the 4 edge slots (lanes with equal sub)
    #pragma unroll
    for (int s = 16; s < 64; s <<= 1) {
        den += __shfl_xor(den, s);
        #pragma unroll
        for (int p = 0; p < FPL; p++) acc[p] += __shfl_xor(acc[p], s);
    }
    float inv = den > 0.f ? 1.f / den : 0.f;

    if (DHT == 128) {
        float v0 = acc[2 * g] * inv, v1 = acc[2 * g + 1] * inv;
        if (ELU_ACT) {
            v0 = v0 > 0.f ? v0 : (__expf(v0) - 1.f);
            v1 = v1 > 0.f ? v1 : (__expf(v1) - 1.f);
        }
        *(float2*)&out[(size_t)r * DHT + sub * FPL + 2 * g] = make_float2(v0, v1);
    } else {
        float v0 = acc[g] * inv;
        if (ELU_ACT) v0 = v0 > 0.f ? v0 : (__expf(v0) - 1.f);
        out[(size_t)r * DHT + sub * FPL + g] = v0;
    }
}

// ---------------- launcher ----------------

extern "C" void kernel_launch(void* const* d_in, const int* in_sizes, int n_in,
                              void* d_out, int out_size, void* d_ws, size_t ws_size,
                              hipStream_t stream) {
    const float* x    = (const float*)d_in[0];
    const int*   ei   = (const int*)d_in[1];
    const float* Win  = (const float*)d_in[2];
    const float* bin  = (const float*)d_in[3];
    const float* ahid = (const float*)d_in[4];
    const float* Whid = (const float*)d_in[5];
    const float* aout = (const float*)d_in[6];
    const float* Wout = (const float*)d_in[7];
    float* out = (float*)d_out;

    const int N_ = in_sizes[0] / 128;
    const int E_ = in_sizes[1] / 2;

    char* p = (char*)d_ws;
    auto alloc = [&](size_t bytes) {
        char* q = p;
        p += (bytes + 511) & ~(size_t)511;
        return q;
    };
    int* counts = (int*)alloc((size_t)N_ * 4);
    int* tmp    = (int*)alloc((size_t)N_ * 4);
    int* rank   = (int*)alloc((size_t)E_ * 4);
    int* off    = (int*)alloc((size_t)(N_ + 1) * 4);
    int* bsum   = (int*)alloc(4096);
    int* scol   = (int*)alloc((size_t)(E_ + 8) * 4);
    float* ssrc = (float*)alloc((size_t)N_ * 4 * 4);
    float* sdst = (float*)alloc((size_t)N_ * 4 * 4);
    float* bufA = (float*)alloc((size_t)N_ * 128 * 4);               // h (fp32)
    unsigned int* hWb = (unsigned int*)alloc((size_t)N_ * 64 * 4);   // hW bf16 packed
    float* Wcat = (float*)alloc(128 * 128 * 4);

    int NB = (N_ + 255) / 256;
    int EB = (E_ + 255) / 256;
    int RT = (N_ + 127) / 128;
    int NW = (N_ + 3) / 4;

    // CSR by destination (= edge_index[0], the softmax segment key)
    hipMemsetAsync(counts, 0, (size_t)N_ * 4, stream);
    hist_k<<<EB, 256, 0, stream>>>(ei, counts, rank, E_);
    scan_block_k<<<NB, 256, 0, stream>>>(counts, tmp, bsum, N_);
    scan_sums_k<<<1, 512, 0, stream>>>(bsum, NB);
    finalize_k<<<NB, 256, 0, stream>>>(tmp, bsum, off, N_);
    scatter_k<<<EB, 256, 0, stream>>>(ei, rank, off, scol, E_);

    // input linear + ELU (fp32 out)
    gemm_k128<128, true, true, false><<<RT, 256, 0, stream>>>(x, Win, bin, bufA, N_);

    // hidden GAT layers
    for (int l = 0; l < 2; l++) {
        attn_scores<4><<<NW, 256, 0, stream>>>(bufA, ahid + (size_t)l * 4 * 2 * 128, ssrc, sdst, N_);
        repack_k<<<64, 256, 0, stream>>>(Whid + (size_t)l * 4 * 128 * 32, Wcat);
        gemm_k128<128, false, false, true><<<RT, 256, 0, stream>>>(bufA, Wcat, nullptr, hWb, N_);
        edge_agg_v<128, 4, true><<<NW, 256, 0, stream>>>(hWb, ssrc, sdst, off, scol, bufA, N_);
    }

    // output GAT layer (single head, 64 classes, no activation) — bf16 hW gather
    attn_scores<1><<<NW, 256, 0, stream>>>(bufA, aout, ssrc, sdst, N_);
    gemm_k128<64, false, false, true><<<RT, 256, 0, stream>>>(bufA, Wout, nullptr, hWb, N_);
    edge_agg_v<64, 1, false><<<NW, 256, 0, stream>>>(hWb, ssrc, sdst, off, scol, out, N_);
}

// Round 6
// 608.896 us; speedup vs baseline: 2.0010x; 1.2260x over previous
//
#include <hip/hip_runtime.h>
#include <hip/hip_bf16.h>
#include <cstdint>
#include <cstddef>

#define LRELU_ALPHA 0.2f

typedef __attribute__((ext_vector_type(8))) short short8;
typedef __attribute__((ext_vector_type(4))) float f32x4;

__device__ __forceinline__ unsigned short f2bf(float f) {
    unsigned int u = __float_as_uint(f);
    unsigned int r = (u + 0x7fffu + ((u >> 16) & 1u)) >> 16;   // RTN-even
    return (unsigned short)r;
}
__device__ __forceinline__ float bf2f(unsigned int lo16) {
    return __uint_as_float(lo16 << 16);
}
__device__ __forceinline__ unsigned int pk2(float a, float b) {
    return (unsigned int)f2bf(a) | ((unsigned int)f2bf(b) << 16);
}

// ---------------- CSR build ----------------

__global__ void hist_k(const int* __restrict__ ei, int* __restrict__ counts,
                       int* __restrict__ rank, int E_) {
    int e = blockIdx.x * 256 + threadIdx.x;
    if (e < E_) {
        int r = ei[e];
        rank[e] = atomicAdd(&counts[r], 1);
    }
}

__global__ void scan_block_k(const int* __restrict__ counts, int* __restrict__ tmp,
                             int* __restrict__ bsum, int n) {
    __shared__ int s[256];
    int i = blockIdx.x * 256 + threadIdx.x;
    int v = (i < n) ? counts[i] : 0;
    s[threadIdx.x] = v;
    __syncthreads();
    for (int d = 1; d < 256; d <<= 1) {
        int t_ = (threadIdx.x >= d) ? s[threadIdx.x - d] : 0;
        __syncthreads();
        s[threadIdx.x] += t_;
        __syncthreads();
    }
    if (i < n) tmp[i] = s[threadIdx.x];
    if (threadIdx.x == 255) bsum[blockIdx.x] = s[255];
}

__global__ void scan_sums_k(int* bsum, int nb) {
    __shared__ int s[512];
    int v = ((int)threadIdx.x < nb) ? bsum[threadIdx.x] : 0;
    s[threadIdx.x] = v;
    __syncthreads();
    for (int d = 1; d < 512; d <<= 1) {
        int t_ = ((int)threadIdx.x >= d) ? s[threadIdx.x - d] : 0;
        __syncthreads();
        s[threadIdx.x] += t_;
        __syncthreads();
    }
    if ((int)threadIdx.x < nb) bsum[threadIdx.x] = s[threadIdx.x] - v;  // exclusive
}

__global__ void finalize_k(const int* __restrict__ tmp, const int* __restrict__ bsum,
                           int* __restrict__ off, int n) {
    int i = blockIdx.x * 256 + threadIdx.x;
    if (i < n) off[i + 1] = tmp[i] + bsum[blockIdx.x];
    if (i == 0) off[0] = 0;
}

__global__ void scatter_k(const int* __restrict__ ei, const int* __restrict__ rank,
                          const int* __restrict__ off, int* __restrict__ scol, int E_) {
    int e = blockIdx.x * 256 + threadIdx.x;
    if (e < E_) {
        int r = ei[e];
        int pos = off[r] + rank[e];
        scol[pos] = ei[E_ + e];
    }
}

// ---------------- weight repack: src HD heads of [128][KJ/HD] fp32 -> WT[KJ][128] bf16 ----

template <int KJ, int HD>
__global__ void repack_wt(const float* __restrict__ src, unsigned short* __restrict__ wt) {
    int i = blockIdx.x * 256 + threadIdx.x;
    if (i < KJ * 128) {
        int n = i >> 7, k = i & 127;
        constexpr int JW = KJ / HD;
        int hd = n / JW, j = n % JW;
        wt[i] = f2bf(src[(hd * 128 + k) * JW + j]);
    }
}

// ---------------- MFMA GEMM: Y[n, 0:KJ] = act(X[n,0:128] @ W[128,KJ] + bias) -------------
// A: fp32 global, converted in-register to bf16. B: WT[n][k] bf16 staged in LDS
// (+8-short row pad -> conflict-free b128 reads). mfma_f32_16x16x32_bf16; per wave
// a 32-row x KJ strip = 2x(KJ/16) tiles, K=128 in 4 mfma steps.
// C/D layout: col=lane&15, row=(lane>>4)*4+reg.

template <int KJ, bool ELU_ACT, bool BIAS, bool BF16_OUT>
__global__ __launch_bounds__(256) void gemm_mfma(const float* __restrict__ X,
                                                 const unsigned short* __restrict__ WT,
                                                 const float* __restrict__ bias,
                                                 void* __restrict__ Yv, int nRows) {
    constexpr int NT = KJ / 16;          // col tiles per wave
    constexpr int WS = 136;              // padded LDS row stride (shorts)
    __shared__ unsigned short sWT[KJ * WS];
    int t = threadIdx.x;
    for (int i = t; i < KJ * 16; i += 256) {
        int n = i >> 4, k8 = i & 15;
        uint4 v = *(const uint4*)&WT[n * 128 + k8 * 8];
        *(uint4*)&sWT[n * WS + k8 * 8] = v;
    }
    __syncthreads();

    int lane = t & 63;
    int wv = t >> 6;
    int m0 = blockIdx.x * 128 + wv * 32;
    int l16 = lane & 15;
    int q4 = lane >> 4;   // 0..3

    // preload + convert A fragments: afr[kk][rt], A[m=l16(+rt*16)][k=kk*32+q4*8+j]
    short8 afr[4][2];
    #pragma unroll
    for (int rt = 0; rt < 2; rt++) {
        int row = m0 + rt * 16 + l16;
        bool vr = row < nRows;
        const float* xp = X + (size_t)row * 128 + q4 * 8;
        #pragma unroll
        for (int kk = 0; kk < 4; kk++) {
            float4 a0 = make_float4(0.f, 0.f, 0.f, 0.f), a1 = a0;
            if (vr) {
                a0 = *(const float4*)(xp + kk * 32);
                a1 = *(const float4*)(xp + kk * 32 + 4);
            }
            unsigned int u[4];
            u[0] = pk2(a0.x, a0.y); u[1] = pk2(a0.z, a0.w);
            u[2] = pk2(a1.x, a1.y); u[3] = pk2(a1.z, a1.w);
            afr[kk][rt] = *(short8*)u;
        }
    }

    f32x4 acc[2][NT] = {};
    #pragma unroll
    for (int kk = 0; kk < 4; kk++) {
        #pragma unroll
        for (int ct = 0; ct < NT; ct++) {
            int n = ct * 16 + l16;
            short8 bf = *(const short8*)&sWT[n * WS + kk * 32 + q4 * 8];
            #pragma unroll
            for (int rt = 0; rt < 2; rt++)
                acc[rt][ct] = __builtin_amdgcn_mfma_f32_16x16x32_bf16(afr[kk][rt], bf, acc[rt][ct], 0, 0, 0);
        }
    }

    #pragma unroll
    for (int rt = 0; rt < 2; rt++) {
        #pragma unroll
        for (int q = 0; q < 4; q++) {
            int row = m0 + rt * 16 + q4 * 4 + q;
            if (row >= nRows) continue;
            #pragma unroll
            for (int ct = 0; ct < NT; ct++) {
                int colc = ct * 16 + l16;
                float v = acc[rt][ct][q];
                if (BIAS) v += bias[colc];
                if (ELU_ACT) v = v > 0.f ? v : (__expf(v) - 1.f);
                if (BF16_OUT) ((unsigned short*)Yv)[(size_t)row * KJ + colc] = f2bf(v);
                else          ((float*)Yv)[(size_t)row * KJ + colc] = v;
            }
        }
    }
}

// ---------------- attention scores ----------------

template <int H>
__global__ __launch_bounds__(256) void attn_scores(const float* __restrict__ h,
                                                   const float* __restrict__ a,
                                                   float* __restrict__ s_src,
                                                   float* __restrict__ s_dst, int n) {
    __shared__ float sa[H * 2 * 128];
    for (int i = threadIdx.x; i < H * 2 * 128; i += 256) sa[i] = a[i];
    __syncthreads();
    int lane = threadIdx.x & 63, wv = threadIdx.x >> 6;
    int node = blockIdx.x * 4 + wv;
    if (node >= n) return;
    float h0 = h[node * 128 + lane];
    float h1 = h[node * 128 + 64 + lane];
    #pragma unroll
    for (int hd = 0; hd < H; hd++) {
        #pragma unroll
        for (int side = 0; side < 2; side++) {
            const float* av = &sa[(hd * 2 + side) * 128];
            float p = h0 * av[lane] + h1 * av[64 + lane];
            #pragma unroll
            for (int s = 32; s > 0; s >>= 1) p += __shfl_xor(p, s);
            if (lane == 0) {
                float* dst = side ? s_dst : s_src;
                dst[node * H + hd] = p;
            }
        }
    }
}

// ---------------- vectorized edge pass (bf16 hW rows) ----------------
// One wave per dst row. 16 lanes per row-slice; 4 edge slots (g = lane>>4) run
// concurrently; each lane loads FPL features of its slot's edge as packed bf16.
// Tail edges predicated (w=0). Slots combined by shfl_xor(16|32) at the end.
// No softmax max-pass (|logit| small by construction, fp32 exp safe).

template <int DHT, int H, bool ELU_ACT>
__global__ __launch_bounds__(256) void edge_agg_v(const unsigned int* __restrict__ hW2,
                                                  const float* __restrict__ ssrc,
                                                  const float* __restrict__ sdst,
                                                  const int* __restrict__ off,
                                                  const int* __restrict__ scol,
                                                  float* __restrict__ out, int nRows) {
    constexpr int FPL = DHT / 16;   // features per lane: 8 (hidden) or 4 (final)
    constexpr int UPL = FPL / 2;    // packed uints per lane
    int lane = threadIdx.x & 63;
    int sub = lane & 15;
    int g = lane >> 4;
    int wv = threadIdx.x >> 6;
    int r = __builtin_amdgcn_readfirstlane(blockIdx.x * 4 + wv);
    if (r >= nRows) return;
    int begin = off[r], end = off[r + 1];

    int head = (H == 4) ? (sub >> 2) : 0;
    float ssl = ssrc[r * H + head];

    float acc[FPL] = {};
    float den = 0.f;

    for (int i = begin; i < end; i += 8) {
        int iA = i + g, iB = i + 4 + g;
        bool vA = iA < end, vB = iB < end;
        int cA = scol[vA ? iA : begin];
        int cB = scol[vB ? iB : begin];
        float sdA = sdst[cA * H + head];
        float sdB = sdst[cB * H + head];
        unsigned int hA[UPL], hB[UPL];
        int oA = cA * (DHT / 2) + sub * UPL;
        int oB = cB * (DHT / 2) + sub * UPL;
        if (UPL == 4) {
            *(uint4*)hA = *(const uint4*)&hW2[oA];
            *(uint4*)hB = *(const uint4*)&hW2[oB];
        } else {
            *(uint2*)hA = *(const uint2*)&hW2[oA];
            *(uint2*)hB = *(const uint2*)&hW2[oB];
        }
        float lgA = ssl + sdA; lgA = lgA > 0.f ? lgA : LRELU_ALPHA * lgA;
        float wA = vA ? __expf(lgA) : 0.f;
        float lgB = ssl + sdB; lgB = lgB > 0.f ? lgB : LRELU_ALPHA * lgB;
        float wB = vB ? __expf(lgB) : 0.f;
        den += wA + wB;
        #pragma unroll
        for (int q = 0; q < UPL; q++) {
            acc[2 * q]     = fmaf(wA, bf2f(hA[q] & 0xffffu), acc[2 * q]);
            acc[2 * q + 1] = fmaf(wA, bf2f(hA[q] >> 16),     acc[2 * q + 1]);
            acc[2 * q]     = fmaf(wB, bf2f(hB[q] & 0xffffu), acc[2 * q]);
            acc[2 * q + 1] = fmaf(wB, bf2f(hB[q] >> 16),     acc[2 * q + 1]);
        }
    }

    #pragma unroll
    for (int s = 16; s < 64; s <<= 1) {
        den += __shfl_xor(den, s);
        #pragma unroll
        for (int p = 0; p < FPL; p++) acc[p] += __shfl_xor(acc[p], s);
    }
    float inv = den > 0.f ? 1.f / den : 0.f;

    if (DHT == 128) {
        float v0 = acc[2 * g] * inv, v1 = acc[2 * g + 1] * inv;
        if (ELU_ACT) {
            v0 = v0 > 0.f ? v0 : (__expf(v0) - 1.f);
            v1 = v1 > 0.f ? v1 : (__expf(v1) - 1.f);
        }
        *(float2*)&out[(size_t)r * DHT + sub * FPL + 2 * g] = make_float2(v0, v1);
    } else {
        float v0 = acc[g] * inv;
        if (ELU_ACT) v0 = v0 > 0.f ? v0 : (__expf(v0) - 1.f);
        out[(size_t)r * DHT + sub * FPL + g] = v0;
    }
}

// ---------------- launcher ----------------

extern "C" void kernel_launch(void* const* d_in, const int* in_sizes, int n_in,
                              void* d_out, int out_size, void* d_ws, size_t ws_size,
                              hipStream_t stream) {
    const float* x    = (const float*)d_in[0];
    const int*   ei   = (const int*)d_in[1];
    const float* Win  = (const float*)d_in[2];
    const float* bin  = (const float*)d_in[3];
    const float* ahid = (const float*)d_in[4];
    const float* Whid = (const float*)d_in[5];
    const float* aout = (const float*)d_in[6];
    const float* Wout = (const float*)d_in[7];
    float* out = (float*)d_out;

    const int N_ = in_sizes[0] / 128;
    const int E_ = in_sizes[1] / 2;

    char* p = (char*)d_ws;
    auto alloc = [&](size_t bytes) {
        char* q = p;
        p += (bytes + 511) & ~(size_t)511;
        return q;
    };
    int* counts = (int*)alloc((size_t)N_ * 4);
    int* tmp    = (int*)alloc((size_t)N_ * 4);
    int* rank   = (int*)alloc((size_t)E_ * 4);
    int* off    = (int*)alloc((size_t)(N_ + 1) * 4);
    int* bsum   = (int*)alloc(4096);
    int* scol   = (int*)alloc((size_t)(E_ + 8) * 4);
    float* ssrc = (float*)alloc((size_t)N_ * 4 * 4);
    float* sdst = (float*)alloc((size_t)N_ * 4 * 4);
    float* bufA = (float*)alloc((size_t)N_ * 128 * 4);               // h (fp32)
    unsigned int* hWb = (unsigned int*)alloc((size_t)N_ * 64 * 4);   // hW bf16 packed
    unsigned short* WTb = (unsigned short*)alloc(128 * 128 * 2);     // WT bf16

    int NB = (N_ + 255) / 256;
    int EB = (E_ + 255) / 256;
    int RT = (N_ + 127) / 128;
    int NW = (N_ + 3) / 4;

    // CSR by destination (= edge_index[0], the softmax segment key)
    hipMemsetAsync(counts, 0, (size_t)N_ * 4, stream);
    hist_k<<<EB, 256, 0, stream>>>(ei, counts, rank, E_);
    scan_block_k<<<NB, 256, 0, stream>>>(counts, tmp, bsum, N_);
    scan_sums_k<<<1, 512, 0, stream>>>(bsum, NB);
    finalize_k<<<NB, 256, 0, stream>>>(tmp, bsum, off, N_);
    scatter_k<<<EB, 256, 0, stream>>>(ei, rank, off, scol, E_);

    // input linear + ELU (fp32 h out)
    repack_wt<128, 1><<<64, 256, 0, stream>>>(Win, WTb);
    gemm_mfma<128, true, true, false><<<RT, 256, 0, stream>>>(x, WTb, bin, bufA, N_);

    // hidden GAT layers
    for (int l = 0; l < 2; l++) {
        attn_scores<4><<<NW, 256, 0, stream>>>(bufA, ahid + (size_t)l * 4 * 2 * 128, ssrc, sdst, N_);
        repack_wt<128, 4><<<64, 256, 0, stream>>>(Whid + (size_t)l * 4 * 128 * 32, WTb);
        gemm_mfma<128, false, false, true><<<RT, 256, 0, stream>>>(bufA, WTb, nullptr, hWb, N_);
        edge_agg_v<128, 4, true><<<NW, 256, 0, stream>>>(hWb, ssrc, sdst, off, scol, bufA, N_);
    }

    // output GAT layer (single head, 64 classes, no activation) — bf16 hW gather
    attn_scores<1><<<NW, 256, 0, stream>>>(bufA, aout, ssrc, sdst, N_);
    repack_wt<64, 1><<<32, 256, 0, stream>>>(Wout, WTb);
    gemm_mfma<64, false, false, true><<<RT, 256, 0, stream>>>(bufA, WTb, nullptr, hWb, N_);
    edge_agg_v<64, 1, false><<<NW, 256, 0, stream>>>(hWb, ssrc, sdst, off, scol, out, N_);
}

// Round 7
// 522.576 us; speedup vs baseline: 2.3315x; 1.1652x over previous
//
#include <hip/hip_runtime.h>
#include <hip/hip_bf16.h>
#include <cstdint>
#include <cstddef>

#define LRELU_ALPHA 0.2f

typedef __attribute__((ext_vector_type(8))) short short8;
typedef __attribute__((ext_vector_type(4))) float f32x4;

__device__ __forceinline__ unsigned short f2bf(float f) {
    unsigned int u = __float_as_uint(f);
    unsigned int r = (u + 0x7fffu + ((u >> 16) & 1u)) >> 16;   // RTN-even
    return (unsigned short)r;
}
__device__ __forceinline__ float bf2f(unsigned int lo16) {
    return __uint_as_float(lo16 << 16);
}
__device__ __forceinline__ unsigned int pk2(float a, float b) {
    return (unsigned int)f2bf(a) | ((unsigned int)f2bf(b) << 16);
}

// ---------------- CSR build ----------------

__global__ void hist_k(const int* __restrict__ ei, int* __restrict__ counts,
                       int* __restrict__ rank, int E_) {
    int e = blockIdx.x * 256 + threadIdx.x;
    if (e < E_) {
        int r = ei[e];
        rank[e] = atomicAdd(&counts[r], 1);
    }
}

__global__ void scan_block_k(const int* __restrict__ counts, int* __restrict__ tmp,
                             int* __restrict__ bsum, int n) {
    __shared__ int s[256];
    int i = blockIdx.x * 256 + threadIdx.x;
    int v = (i < n) ? counts[i] : 0;
    s[threadIdx.x] = v;
    __syncthreads();
    for (int d = 1; d < 256; d <<= 1) {
        int t_ = (threadIdx.x >= d) ? s[threadIdx.x - d] : 0;
        __syncthreads();
        s[threadIdx.x] += t_;
        __syncthreads();
    }
    if (i < n) tmp[i] = s[threadIdx.x];
    if (threadIdx.x == 255) bsum[blockIdx.x] = s[255];
}

__global__ void scan_sums_k(int* bsum, int nb) {
    __shared__ int s[512];
    int v = ((int)threadIdx.x < nb) ? bsum[threadIdx.x] : 0;
    s[threadIdx.x] = v;
    __syncthreads();
    for (int d = 1; d < 512; d <<= 1) {
        int t_ = ((int)threadIdx.x >= d) ? s[threadIdx.x - d] : 0;
        __syncthreads();
        s[threadIdx.x] += t_;
        __syncthreads();
    }
    if ((int)threadIdx.x < nb) bsum[threadIdx.x] = s[threadIdx.x] - v;  // exclusive
}

__global__ void finalize_k(const int* __restrict__ tmp, const int* __restrict__ bsum,
                           int* __restrict__ off, int n) {
    int i = blockIdx.x * 256 + threadIdx.x;
    if (i < n) off[i + 1] = tmp[i] + bsum[blockIdx.x];
    if (i == 0) off[0] = 0;
}

__global__ void scatter_k(const int* __restrict__ ei, const int* __restrict__ rank,
                          const int* __restrict__ off, int* __restrict__ scol, int E_) {
    int e = blockIdx.x * 256 + threadIdx.x;
    if (e < E_) {
        int r = ei[e];
        int pos = off[r] + rank[e];
        scol[pos] = ei[E_ + e];
    }
}

// ---------------- weight repack: src HD heads of [128][KJ/HD] fp32 -> WT[KJ][128] bf16 ----

template <int KJ, int HD>
__global__ void repack_wt(const float* __restrict__ src, unsigned short* __restrict__ wt) {
    int i = blockIdx.x * 256 + threadIdx.x;
    if (i < KJ * 128) {
        int n = i >> 7, k = i & 127;
        constexpr int JW = KJ / HD;
        int hd = n / JW, j = n % JW;
        wt[i] = f2bf(src[(hd * 128 + k) * JW + j]);
    }
}

// ---------------- MFMA GEMM: Y[n, 0:KJ] = act(X[n,0:128] @ W[128,KJ] + bias) -------------
// A: fp32 (converted in-register) or packed bf16 (ABF16). B: WT[n][k] bf16 in LDS
// (+8-short row pad). mfma_f32_16x16x32_bf16; per wave 32-row x KJ strip.
// C/D layout: col=lane&15, row=(lane>>4)*4+reg.

template <int KJ, bool ELU_ACT, bool BIAS, bool BF16_OUT, bool ABF16>
__global__ __launch_bounds__(256) void gemm_mfma(const void* __restrict__ Xv,
                                                 const unsigned short* __restrict__ WT,
                                                 const float* __restrict__ bias,
                                                 void* __restrict__ Yv, int nRows) {
    constexpr int NT = KJ / 16;
    constexpr int WS = 136;
    __shared__ unsigned short sWT[KJ * WS];
    int t = threadIdx.x;
    for (int i = t; i < KJ * 16; i += 256) {
        int n = i >> 4, k8 = i & 15;
        uint4 v = *(const uint4*)&WT[n * 128 + k8 * 8];
        *(uint4*)&sWT[n * WS + k8 * 8] = v;
    }
    __syncthreads();

    int lane = t & 63;
    int wv = t >> 6;
    int m0 = blockIdx.x * 128 + wv * 32;
    int l16 = lane & 15;
    int q4 = lane >> 4;

    short8 afr[4][2];
    #pragma unroll
    for (int rt = 0; rt < 2; rt++) {
        int row = m0 + rt * 16 + l16;
        bool vr = row < nRows;
        if (ABF16) {
            const unsigned int* xp = (const unsigned int*)Xv + (size_t)row * 64 + q4 * 4;
            #pragma unroll
            for (int kk = 0; kk < 4; kk++) {
                uint4 u = make_uint4(0u, 0u, 0u, 0u);
                if (vr) u = *(const uint4*)(xp + kk * 16);
                afr[kk][rt] = *(short8*)&u;
            }
        } else {
            const float* xp = (const float*)Xv + (size_t)row * 128 + q4 * 8;
            #pragma unroll
            for (int kk = 0; kk < 4; kk++) {
                float4 a0 = make_float4(0.f, 0.f, 0.f, 0.f), a1 = a0;
                if (vr) {
                    a0 = *(const float4*)(xp + kk * 32);
                    a1 = *(const float4*)(xp + kk * 32 + 4);
                }
                unsigned int u[4];
                u[0] = pk2(a0.x, a0.y); u[1] = pk2(a0.z, a0.w);
                u[2] = pk2(a1.x, a1.y); u[3] = pk2(a1.z, a1.w);
                afr[kk][rt] = *(short8*)u;
            }
        }
    }

    f32x4 acc[2][NT] = {};
    #pragma unroll
    for (int kk = 0; kk < 4; kk++) {
        #pragma unroll
        for (int ct = 0; ct < NT; ct++) {
            int n = ct * 16 + l16;
            short8 bf = *(const short8*)&sWT[n * WS + kk * 32 + q4 * 8];
            #pragma unroll
            for (int rt = 0; rt < 2; rt++)
                acc[rt][ct] = __builtin_amdgcn_mfma_f32_16x16x32_bf16(afr[kk][rt], bf, acc[rt][ct], 0, 0, 0);
        }
    }

    #pragma unroll
    for (int rt = 0; rt < 2; rt++) {
        #pragma unroll
        for (int q = 0; q < 4; q++) {
            int row = m0 + rt * 16 + q4 * 4 + q;
            if (row >= nRows) continue;
            #pragma unroll
            for (int ct = 0; ct < NT; ct++) {
                int colc = ct * 16 + l16;
                float v = acc[rt][ct][q];
                if (BIAS) v += bias[colc];
                if (ELU_ACT) v = v > 0.f ? v : (__expf(v) - 1.f);
                if (BF16_OUT) ((unsigned short*)Yv)[(size_t)row * KJ + colc] = f2bf(v);
                else          ((float*)Yv)[(size_t)row * KJ + colc] = v;
            }
        }
    }
}

// ---------------- attention scores from packed-bf16 h (layer 0 only) ----------------

template <int H>
__global__ __launch_bounds__(256) void attn_scores_bf(const unsigned int* __restrict__ h2,
                                                      const float* __restrict__ a,
                                                      float* __restrict__ s_src,
                                                      float* __restrict__ s_dst, int n) {
    __shared__ float sa[H * 2 * 128];
    for (int i = threadIdx.x; i < H * 2 * 128; i += 256) sa[i] = a[i];
    __syncthreads();
    int lane = threadIdx.x & 63, wv = threadIdx.x >> 6;
    int node = blockIdx.x * 4 + wv;
    if (node >= n) return;
    unsigned int hv = h2[(size_t)node * 64 + lane];
    float v0 = bf2f(hv & 0xffffu), v1 = bf2f(hv >> 16);
    #pragma unroll
    for (int hd = 0; hd < H; hd++) {
        #pragma unroll
        for (int side = 0; side < 2; side++) {
            const float2 aa = *(const float2*)&sa[(hd * 2 + side) * 128 + 2 * lane];
            float p = v0 * aa.x + v1 * aa.y;
            #pragma unroll
            for (int s = 32; s > 0; s >>= 1) p += __shfl_xor(p, s);
            if (lane == 0) {
                float* dst = side ? s_dst : s_src;
                dst[node * H + hd] = p;
            }
        }
    }
}

// ---------------- vectorized edge pass (bf16 hW) + fused next-layer attention ------------
// One wave per dst row; 16 lanes per row-slice, 4 edge slots (g=lane>>4).
// After slot reduction every lane holds its 8 output features; slot g computes
// 2 of the 8 (head,side) score partials vs a_next (LDS), shfl-reduced over subs.
// No softmax max-pass (|logit| small by construction).

template <int DHT, int H, bool ELU_ACT, int HN, bool BF16O>
__global__ __launch_bounds__(256) void edge_agg_v(const unsigned int* __restrict__ hW2,
                                                  const float* __restrict__ ssrc,
                                                  const float* __restrict__ sdst,
                                                  const int* __restrict__ off,
                                                  const int* __restrict__ scol,
                                                  void* __restrict__ outv,
                                                  const float* __restrict__ a_next,
                                                  float* __restrict__ ssrc_n,
                                                  float* __restrict__ sdst_n, int nRows) {
    constexpr int FPL = DHT / 16;   // features per lane
    constexpr int UPL = FPL / 2;    // packed uints per lane
    constexpr int NC = (HN > 0) ? 2 * HN : 1;
    __shared__ float sAN[NC * 128];
    if (HN > 0) {
        for (int i = threadIdx.x; i < NC * 128; i += 256) sAN[i] = a_next[i];
        __syncthreads();
    }
    int lane = threadIdx.x & 63;
    int sub = lane & 15;
    int g = lane >> 4;
    int wv = threadIdx.x >> 6;
    int r = __builtin_amdgcn_readfirstlane(blockIdx.x * 4 + wv);
    if (r >= nRows) return;
    int begin = off[r], end = off[r + 1];

    int head = (H == 4) ? (sub >> 2) : 0;
    float ssl = ssrc[r * H + head];

    float acc[FPL] = {};
    float den = 0.f;

    for (int i = begin; i < end; i += 8) {
        int iA = i + g, iB = i + 4 + g;
        bool vA = iA < end, vB = iB < end;
        int cA = scol[vA ? iA : begin];
        int cB = scol[vB ? iB : begin];
        float sdA = sdst[cA * H + head];
        float sdB = sdst[cB * H + head];
        unsigned int hA[UPL], hB[UPL];
        int oA = cA * (DHT / 2) + sub * UPL;
        int oB = cB * (DHT / 2) + sub * UPL;
        if (UPL == 4) {
            *(uint4*)hA = *(const uint4*)&hW2[oA];
            *(uint4*)hB = *(const uint4*)&hW2[oB];
        } else {
            *(uint2*)hA = *(const uint2*)&hW2[oA];
            *(uint2*)hB = *(const uint2*)&hW2[oB];
        }
        float lgA = ssl + sdA; lgA = lgA > 0.f ? lgA : LRELU_ALPHA * lgA;
        float wA = vA ? __expf(lgA) : 0.f;
        float lgB = ssl + sdB; lgB = lgB > 0.f ? lgB : LRELU_ALPHA * lgB;
        float wB = vB ? __expf(lgB) : 0.f;
        den += wA + wB;
        #pragma unroll
        for (int q = 0; q < UPL; q++) {
            acc[2 * q]     = fmaf(wA, bf2f(hA[q] & 0xffffu), acc[2 * q]);
            acc[2 * q + 1] = fmaf(wA, bf2f(hA[q] >> 16),     acc[2 * q + 1]);
            acc[2 * q]     = fmaf(wB, bf2f(hB[q] & 0xffffu), acc[2 * q]);
            acc[2 * q + 1] = fmaf(wB, bf2f(hB[q] >> 16),     acc[2 * q + 1]);
        }
    }

    #pragma unroll
    for (int s = 16; s < 64; s <<= 1) {
        den += __shfl_xor(den, s);
        #pragma unroll
        for (int p = 0; p < FPL; p++) acc[p] += __shfl_xor(acc[p], s);
    }
    float inv = den > 0.f ? 1.f / den : 0.f;

    float v[FPL];
    #pragma unroll
    for (int p = 0; p < FPL; p++) {
        float tv = acc[p] * inv;
        if (ELU_ACT) tv = tv > 0.f ? tv : (__expf(tv) - 1.f);
        v[p] = tv;
    }

    if (DHT == 128) {
        if (BF16O)
            ((unsigned int*)outv)[(size_t)r * 64 + sub * 4 + g] = pk2(v[2 * g], v[2 * g + 1]);
        else
            *(float2*)&((float*)outv)[(size_t)r * 128 + sub * 8 + 2 * g] =
                make_float2(v[2 * g], v[2 * g + 1]);
    } else {
        ((float*)outv)[(size_t)r * DHT + sub * FPL + g] = v[g];
    }

    if (HN > 0) {
        constexpr int CPG = (HN == 4) ? 2 : 1;
        #pragma unroll
        for (int cc = 0; cc < CPG; cc++) {
            int c = (HN == 4) ? (g * 2 + cc) : (g & 1);
            const float* ap = &sAN[c * 128 + sub * FPL];
            float partial = 0.f;
            #pragma unroll
            for (int p = 0; p < FPL; p++) partial += v[p] * ap[p];
            #pragma unroll
            for (int s = 1; s < 16; s <<= 1) partial += __shfl_xor(partial, s);
            if (sub == 0 && (HN == 4 || g < 2)) {
                int hd = c >> 1;
                float* dst = (c & 1) ? sdst_n : ssrc_n;
                dst[r * HN + hd] = partial;
            }
        }
    }
}

// ---------------- launcher ----------------

extern "C" void kernel_launch(void* const* d_in, const int* in_sizes, int n_in,
                              void* d_out, int out_size, void* d_ws, size_t ws_size,
                              hipStream_t stream) {
    const float* x    = (const float*)d_in[0];
    const int*   ei   = (const int*)d_in[1];
    const float* Win  = (const float*)d_in[2];
    const float* bin  = (const float*)d_in[3];
    const float* ahid = (const float*)d_in[4];
    const float* Whid = (const float*)d_in[5];
    const float* aout = (const float*)d_in[6];
    const float* Wout = (const float*)d_in[7];
    float* out = (float*)d_out;

    const int N_ = in_sizes[0] / 128;
    const int E_ = in_sizes[1] / 2;

    char* p = (char*)d_ws;
    auto alloc = [&](size_t bytes) {
        char* q = p;
        p += (bytes + 511) & ~(size_t)511;
        return q;
    };
    int* counts = (int*)alloc((size_t)N_ * 4);
    int* tmp    = (int*)alloc((size_t)N_ * 4);
    int* rank   = (int*)alloc((size_t)E_ * 4);
    int* off    = (int*)alloc((size_t)(N_ + 1) * 4);
    int* bsum   = (int*)alloc(4096);
    int* scol   = (int*)alloc((size_t)(E_ + 8) * 4);
    float* ssrcA = (float*)alloc((size_t)N_ * 4 * 4);
    float* sdstA = (float*)alloc((size_t)N_ * 4 * 4);
    float* ssrcB = (float*)alloc((size_t)N_ * 4 * 4);
    float* sdstB = (float*)alloc((size_t)N_ * 4 * 4);
    unsigned int* hb  = (unsigned int*)alloc((size_t)N_ * 64 * 4);   // h  bf16 packed
    unsigned int* hWb = (unsigned int*)alloc((size_t)N_ * 64 * 4);   // hW bf16 packed
    unsigned short* WTb = (unsigned short*)alloc(128 * 128 * 2);     // WT bf16

    int NB = (N_ + 255) / 256;
    int EB = (E_ + 255) / 256;
    int RT = (N_ + 127) / 128;
    int NW = (N_ + 3) / 4;

    // CSR by destination (= edge_index[0], the softmax segment key)
    hipMemsetAsync(counts, 0, (size_t)N_ * 4, stream);
    hist_k<<<EB, 256, 0, stream>>>(ei, counts, rank, E_);
    scan_block_k<<<NB, 256, 0, stream>>>(counts, tmp, bsum, N_);
    scan_sums_k<<<1, 512, 0, stream>>>(bsum, NB);
    finalize_k<<<NB, 256, 0, stream>>>(tmp, bsum, off, N_);
    scatter_k<<<EB, 256, 0, stream>>>(ei, rank, off, scol, E_);

    // input linear + ELU -> h0 bf16
    repack_wt<128, 1><<<64, 256, 0, stream>>>(Win, WTb);
    gemm_mfma<128, true, true, true, false><<<RT, 256, 0, stream>>>(x, WTb, bin, hb, N_);

    // layer-0 attention scores (reads bf16 h0)
    attn_scores_bf<4><<<NW, 256, 0, stream>>>(hb, ahid, ssrcA, sdstA, N_);

    // hidden layer 1: hW0 = h0 @ Wcat0 ; aggregate -> h1 bf16 (+ scores for a_hid[1])
    repack_wt<128, 4><<<64, 256, 0, stream>>>(Whid, WTb);
    gemm_mfma<128, false, false, true, true><<<RT, 256, 0, stream>>>(hb, WTb, nullptr, hWb, N_);
    edge_agg_v<128, 4, true, 4, true><<<NW, 256, 0, stream>>>(
        hWb, ssrcA, sdstA, off, scol, hb, ahid + 4 * 2 * 128, ssrcB, sdstB, N_);

    // hidden layer 2: hW1 = h1 @ Wcat1 ; aggregate -> h2 bf16 (+ scores for a_out)
    repack_wt<128, 4><<<64, 256, 0, stream>>>(Whid + (size_t)4 * 128 * 32, WTb);
    gemm_mfma<128, false, false, true, true><<<RT, 256, 0, stream>>>(hb, WTb, nullptr, hWb, N_);
    edge_agg_v<128, 4, true, 1, true><<<NW, 256, 0, stream>>>(
        hWb, ssrcB, sdstB, off, scol, hb, aout, ssrcA, sdstA, N_);

    // output layer: hW2 = h2 @ Wout ; aggregate -> out fp32
    repack_wt<64, 1><<<32, 256, 0, stream>>>(Wout, WTb);
    gemm_mfma<64, false, false, true, true><<<RT, 256, 0, stream>>>(hb, WTb, nullptr, hWb, N_);
    edge_agg_v<64, 1, false, 0, false><<<NW, 256, 0, stream>>>(
        hWb, ssrcA, sdstA, off, scol, out, nullptr, nullptr, nullptr, N_);
}